// Round 5
// baseline (226.306 us; speedup 1.0000x reference)
//
#include <hip/hip_runtime.h>
#include <math.h>

typedef unsigned short ushort_t;
typedef float f32x4 __attribute__((ext_vector_type(4)));
typedef __bf16 bf16x8 __attribute__((ext_vector_type(8)));
typedef ushort_t u16x8 __attribute__((ext_vector_type(8)));

#define DEVFN __device__ __forceinline__

DEVFN ushort_t f2bf(float f) {
  unsigned int u = __float_as_uint(f);
  u += 0x7FFFu + ((u >> 16) & 1u);   // round-to-nearest-even
  return (ushort_t)(u >> 16);
}
DEVFN float bf2f(ushort_t u) { return __uint_as_float((unsigned int)u << 16); }

DEVFN void gload(const ushort_t* src, char* dst) {
  __builtin_amdgcn_global_load_lds(
      (const __attribute__((address_space(1))) unsigned int*)src,
      (__attribute__((address_space(3))) unsigned int*)dst, 16, 0, 0);
}

#define N_TOK  2048
#define HDIM   768
#define TCOLS  8448     // 2*I + 3*H
#define FFI    3072
#define NHEADS 12
#define HD     64
#define NSEG   8
#define SEGLEN 256
#define ABCOLS 3840     // H + I
#define KSPLIT 5
#define KCHUNK 768      // 3840 / 5

// ---------------------------------------------------------------- transpose + f32->bf16
__global__ void transpose_convert(const float* __restrict__ in, ushort_t* __restrict__ out,
                                  int R, int C) {
  in  += (size_t)blockIdx.z * R * C;
  out += (size_t)blockIdx.z * R * C;
  __shared__ ushort_t tile[32][33];
  const int tc = blockIdx.x * 32, tr = blockIdx.y * 32;
  const int tx = threadIdx.x, ty = threadIdx.y;   // 32 x 8
#pragma unroll
  for (int i = 0; i < 4; ++i)
    tile[ty + i * 8][tx] = f2bf(in[(size_t)(tr + ty + i * 8) * C + tc + tx]);
  __syncthreads();
#pragma unroll
  for (int i = 0; i < 4; ++i)
    out[(size_t)(tc + ty + i * 8) * R + tr + tx] = tile[tx][ty + i * 8];
}

// ---------------------------------------------------------------- rope tables
__global__ __launch_bounds__(256) void sincos_kernel(const float* __restrict__ ages,
                              float* __restrict__ sintab, float* __restrict__ costab) {
  const int n = blockIdx.x * 8 + (threadIdx.x >> 5), k = threadIdx.x & 31;
  const float e = (2.0f * (float)k) / 31.0f;
  const float inv = expf(-e * logf(10000.0f));
  const float t = ages[n] * inv;
  const float s = sinf(t), c = cosf(t);
  sintab[n * HD + 2 * k] = s; sintab[n * HD + 2 * k + 1] = s;
  costab[n * HD + 2 * k] = c; costab[n * HD + 2 * k + 1] = c;
}

// ---------------------------------------------------------------- rmsnorm (plain)
__global__ __launch_bounds__(256) void rms_kernel(
    const float* __restrict__ in, const int* __restrict__ tokens,
    const float* __restrict__ w, const float* __restrict__ time_data,
    float* __restrict__ out_f32, ushort_t* __restrict__ out_bf16, const int mode) {
  const int row = blockIdx.x;
  const float* src = in + (size_t)(mode == 0 ? tokens[row] : row) * HDIM;
  float v[3]; float ss = 0.f;
#pragma unroll
  for (int i = 0; i < 3; ++i) { v[i] = src[threadIdx.x + i * 256]; ss += v[i] * v[i]; }
#pragma unroll
  for (int off = 1; off < 64; off <<= 1) ss += __shfl_xor(ss, off);
  __shared__ float part[4];
  if ((threadIdx.x & 63) == 0) part[threadIdx.x >> 6] = ss;
  __syncthreads();
  const float tot = part[0] + part[1] + part[2] + part[3];
  const float rs = rsqrtf(tot * (1.0f / HDIM) + 1e-6f);
#pragma unroll
  for (int i = 0; i < 3; ++i) {
    const int c = threadIdx.x + i * 256;
    float val = v[i] * rs * w[c];
    if (mode == 1) {
      if (c >= HDIM - 4) {
        const float td = time_data[row * 2 + (c & 1)];
        val = (c >= HDIM - 2) ? td * td : td;
      }
      out_bf16[(size_t)row * HDIM + c] = f2bf(val);
    } else {
      out_f32[(size_t)row * HDIM + c] = val;
    }
  }
}

// ---------------------------------------------------------------- fused splitK-reduce + residual + rmsnorm
__global__ __launch_bounds__(256) void rms_fused(
    const float* __restrict__ cpart, float* __restrict__ x,
    const float* __restrict__ w, const float* __restrict__ time_data,
    float* __restrict__ out_f32, ushort_t* __restrict__ out_bf16, const int mode) {
  const int row = blockIdx.x;
  const size_t stride = (size_t)N_TOK * HDIM;
  float v[3]; float ss = 0.f;
#pragma unroll
  for (int i = 0; i < 3; ++i) {
    const size_t idx = (size_t)row * HDIM + threadIdx.x + i * 256;
    float s = x[idx];
#pragma unroll
    for (int z = 0; z < KSPLIT; ++z) s += cpart[z * stride + idx];
    if (mode == 1) x[idx] = s;
    v[i] = s; ss += s * s;
  }
#pragma unroll
  for (int off = 1; off < 64; off <<= 1) ss += __shfl_xor(ss, off);
  __shared__ float part[4];
  if ((threadIdx.x & 63) == 0) part[threadIdx.x >> 6] = ss;
  __syncthreads();
  const float tot = part[0] + part[1] + part[2] + part[3];
  const float rs = rsqrtf(tot * (1.0f / HDIM) + 1e-6f);
#pragma unroll
  for (int i = 0; i < 3; ++i) {
    const int c = threadIdx.x + i * 256;
    float val = v[i] * rs * w[c];
    if (mode == 1) {
      if (c >= HDIM - 4) {
        const float td = time_data[row * 2 + (c & 1)];
        val = (c >= HDIM - 2) ? td * td : td;
      }
      out_bf16[(size_t)row * HDIM + c] = f2bf(val);
    } else {
      out_f32[(size_t)row * HDIM + c] = val;
    }
  }
}

// ---------------------------------------------------------------- GEMM1: 128x176 tile, grid 768 = 3/CU exact
// A: 2048x768 bf16 rm; BT: 8448x768 bf16 rm; C: 2048x8448 bf16. BK=32, 24 K-steps.
// LDS B padded to 192 rows (rows 176..191 staged from adjacent ws memory, frag n=5/wc=1 discarded).
#define G1_NT 24
#define G1_ABYT 8192          // 128x32 bf16
#define G1_BUF  20480         // + 192x32 bf16 (12288)

DEVFN int swz64(int p) {      // 64B rows: slot bits 4-5 ^= rowbits(0-1)^rowbits(2-3)
  const int g = ((p >> 6) & 3) ^ ((p >> 8) & 3);
  return p ^ (g << 4);
}

DEVFN void g1z_stage(const ushort_t* __restrict__ A, const ushort_t* __restrict__ BT,
                     int m0, int n0, int kt_el, char* buf, int tid) {
#pragma unroll
  for (int i = 0; i < 2; ++i) {       // A: 8KB, 2 rounds
    const int q = swz64(i * 4096 + tid * 16);
    const ushort_t* src = A + (size_t)(m0 + (q >> 6)) * HDIM + kt_el + ((q & 63) >> 1);
    gload(src, buf + i * 4096 + ((tid >> 6) << 10));
  }
#pragma unroll
  for (int i = 0; i < 3; ++i) {       // B: 12KB (192 rows), 3 rounds
    const int q = swz64(i * 4096 + tid * 16);
    const ushort_t* src = BT + (size_t)(n0 + (q >> 6)) * HDIM + kt_el + ((q & 63) >> 1);
    gload(src, buf + G1_ABYT + i * 4096 + ((tid >> 6) << 10));
  }
}

__global__ __launch_bounds__(256, 3) void gemm1z(
    const ushort_t* __restrict__ A, const ushort_t* __restrict__ BT,
    ushort_t* __restrict__ Cbf) {
  __shared__ __align__(16) char smem[2 * G1_BUF];     // 40 KiB
  const int tid = threadIdx.x;
  const int l = tid & 63, l15 = l & 15, l4 = l >> 4;
  const int wid = tid >> 6, wr = wid >> 1, wc = wid & 1;   // 2x2 waves
  const int bid = (int)blockIdx.x;
  const int wg = (bid & 7) * 96 + (bid >> 3);         // XCD-contiguous, nt-major
  const int nt = wg >> 4, mt = wg & 15;               // 48 N-tiles x 16 M-tiles
  const int m0 = mt * 128, n0 = nt * 176;

  f32x4 acc[4][6] = {};

  g1z_stage(A, BT, m0, n0, 0,  smem, tid);
  g1z_stage(A, BT, m0, n0, 32, smem + G1_BUF, tid);
  asm volatile("s_waitcnt vmcnt(5)" ::: "memory");    // tile 0 landed
  __builtin_amdgcn_s_barrier();
  __builtin_amdgcn_sched_barrier(0);

  for (int t = 0; t < G1_NT; ++t) {
    const char* bufA = smem + (t & 1) * G1_BUF;
    const char* bufB = bufA + G1_ABYT;
    bf16x8 a4[4], b6[6];
#pragma unroll
    for (int m = 0; m < 4; ++m) {
      const int p = (wr * 64 + m * 16 + l15) * 64 + l4 * 16;
      a4[m] = *(const bf16x8*)(bufA + swz64(p));
    }
#pragma unroll
    for (int n = 0; n < 6; ++n) {
      const int p = (wc * 96 + n * 16 + l15) * 64 + l4 * 16;
      b6[n] = *(const bf16x8*)(bufB + swz64(p));
    }
#pragma unroll
    for (int m = 0; m < 4; ++m)
#pragma unroll
      for (int n = 0; n < 6; ++n)
        acc[m][n] = __builtin_amdgcn_mfma_f32_16x16x32_bf16(a4[m], b6[n], acc[m][n], 0, 0, 0);

    if (t == G1_NT - 1) break;
    __builtin_amdgcn_sched_barrier(0);
    __builtin_amdgcn_s_barrier();                     // reads of buf[t&1] done
    if (t + 2 < G1_NT) {
      g1z_stage(A, BT, m0, n0, (t + 2) * 32, smem + (t & 1) * G1_BUF, tid);
      asm volatile("s_waitcnt vmcnt(5)" ::: "memory"); // tile t+1 landed
    } else {
      asm volatile("s_waitcnt vmcnt(0)" ::: "memory");
    }
    __builtin_amdgcn_s_barrier();
    __builtin_amdgcn_sched_barrier(0);
  }

#pragma unroll
  for (int m = 0; m < 4; ++m)
#pragma unroll
    for (int n = 0; n < 6; ++n) {
      if (wc == 1 && n == 5) continue;                // pad fragment, discard
#pragma unroll
      for (int r = 0; r < 4; ++r) {
        const int row = m0 + wr * 64 + m * 16 + l4 * 4 + r;
        const int col = n0 + wc * 96 + n * 16 + l15;
        Cbf[(size_t)row * TCOLS + col] = f2bf(acc[m][n][r]);
      }
    }
}

// ---------------------------------------------------------------- GEMM2: 128x128 split-K, pipelined
#define G2_NT 12              // KCHUNK / 64
#define G2_BUF 32768          // A 16KB + B 16KB

DEVFN int swz128(int p) { return p ^ (((p >> 7) & 7) << 4); }   // 128B rows

DEVFN void g2_stage(const ushort_t* __restrict__ A, const ushort_t* __restrict__ BT,
                    int m0, int n0, int kt_el, char* buf, int tid) {
#pragma unroll
  for (int i = 0; i < 8; ++i) {
    const int p = i * 4096 + tid * 16;
    const bool isA = p < 16384;
    const int q = swz128(isA ? p : p - 16384);
    const int row = q >> 7, colel = (q & 127) >> 1;
    const ushort_t* src = (isA ? A + (size_t)(m0 + row) * ABCOLS
                               : BT + (size_t)(n0 + row) * ABCOLS) + kt_el + colel;
    gload(src, buf + i * 4096 + ((tid >> 6) << 10));
  }
}

__global__ __launch_bounds__(256, 2) void gemm2_splitk(
    const ushort_t* __restrict__ A, const ushort_t* __restrict__ BT,
    float* __restrict__ Cp) {
  __shared__ __align__(16) char smem[2 * G2_BUF];     // 64 KiB
  const int tid = threadIdx.x;
  const int l = tid & 63, l15 = l & 15, l4 = l >> 4;
  const int w = tid >> 6, wr = w >> 1, wc = w & 1;
  const int m0 = blockIdx.y * 128, n0 = blockIdx.x * 128;
  const int kt0 = blockIdx.z * KCHUNK;

  f32x4 acc[4][4] = {};

  g2_stage(A, BT, m0, n0, kt0, smem, tid);
  g2_stage(A, BT, m0, n0, kt0 + 64, smem + G2_BUF, tid);
  asm volatile("s_waitcnt vmcnt(8)" ::: "memory");
  __builtin_amdgcn_s_barrier();
  __builtin_amdgcn_sched_barrier(0);

  for (int t = 0; t < G2_NT; ++t) {
    const char* bufA = smem + (t & 1) * G2_BUF;
    const char* bufB = bufA + 16384;
    bf16x8 af[4][2], bv[4][2];
#pragma unroll
    for (int kk = 0; kk < 2; ++kk) {
#pragma unroll
      for (int mi = 0; mi < 4; ++mi) {
        const int p = (wr * 64 + mi * 16 + l15) * 128 + kk * 64 + l4 * 16;
        af[mi][kk] = *(const bf16x8*)(bufA + swz128(p));
      }
#pragma unroll
      for (int ni = 0; ni < 4; ++ni) {
        const int p = (wc * 64 + ni * 16 + l15) * 128 + kk * 64 + l4 * 16;
        bv[ni][kk] = *(const bf16x8*)(bufB + swz128(p));
      }
    }
#pragma unroll
    for (int kk = 0; kk < 2; ++kk)
#pragma unroll
      for (int mi = 0; mi < 4; ++mi)
#pragma unroll
        for (int ni = 0; ni < 4; ++ni)
          acc[mi][ni] = __builtin_amdgcn_mfma_f32_16x16x32_bf16(af[mi][kk], bv[ni][kk], acc[mi][ni], 0, 0, 0);

    if (t == G2_NT - 1) break;
    __builtin_amdgcn_sched_barrier(0);
    __builtin_amdgcn_s_barrier();
    if (t + 2 < G2_NT) {
      g2_stage(A, BT, m0, n0, kt0 + (t + 2) * 64, smem + (t & 1) * G2_BUF, tid);
      asm volatile("s_waitcnt vmcnt(8)" ::: "memory");
    } else {
      asm volatile("s_waitcnt vmcnt(0)" ::: "memory");
    }
    __builtin_amdgcn_s_barrier();
    __builtin_amdgcn_sched_barrier(0);
  }

  float* Cz = Cp + (size_t)blockIdx.z * N_TOK * HDIM;
#pragma unroll
  for (int mi = 0; mi < 4; ++mi)
#pragma unroll
    for (int ni = 0; ni < 4; ++ni)
#pragma unroll
      for (int r = 0; r < 4; ++r) {
        const int row = m0 + wr * 64 + mi * 16 + l4 * 4 + r;
        const int col = n0 + wc * 64 + ni * 16 + l15;
        Cz[(size_t)row * HDIM + col] = acc[mi][ni][r];
      }
}

// ---------------------------------------------------------------- rope + qkv extraction (bf16 t)
__global__ __launch_bounds__(256) void extract_kernel(
    const ushort_t* __restrict__ t, const float* __restrict__ sintab, const float* __restrict__ costab,
    ushort_t* __restrict__ qr, ushort_t* __restrict__ kr, ushort_t* __restrict__ vT) {
  const int nb = blockIdx.x, h = blockIdx.y;
  const int tid = threadIdx.x;
  __shared__ ushort_t vt_tile[64][65];
#pragma unroll
  for (int i = 0; i < 16; ++i) {
    const int flat = tid + 256 * i;
    const int nl = flat >> 6, d = flat & 63;
    const int n = nb * 64 + nl;
    const size_t base = (size_t)n * TCOLS + 2 * FFI + h * HD;
    const float sn = sintab[n * HD + d], cs = costab[n * HD + d];
    const float xq = bf2f(t[base + d]), xq2 = bf2f(t[base + (d ^ 1)]);
    const float rq = (d & 1) ? xq2 : -xq2;
    qr[((size_t)h * N_TOK + n) * HD + d] = f2bf(xq * cs + rq * sn);
    const float xk = bf2f(t[base + HDIM + d]), xk2 = bf2f(t[base + HDIM + (d ^ 1)]);
    const float rk = (d & 1) ? xk2 : -xk2;
    kr[((size_t)h * N_TOK + n) * HD + d] = f2bf(xk * cs + rk * sn);
    vt_tile[nl][d] = t[base + 2 * HDIM + d];
  }
  __syncthreads();
#pragma unroll
  for (int i = 0; i < 16; ++i) {
    const int flat = tid + 256 * i;
    const int dr = flat >> 6, nl = flat & 63;
    vT[((size_t)h * HD + dr) * N_TOK + nb * 64 + nl] = vt_tile[nl][dr];
  }
}

// ---------------------------------------------------------------- segment attention, 16-row q-tiles
// grid (NH, NSEG, 4): block z -> q-tiles [4z, 4z+3], each wave exactly z+1 kb-tiles (uniform).
__global__ __launch_bounds__(256) void attn_kernel(
    const ushort_t* __restrict__ qr, const ushort_t* __restrict__ kr,
    const ushort_t* __restrict__ vT, ushort_t* __restrict__ ab) {
  const int h = blockIdx.x, seg = blockIdx.y, z = blockIdx.z;
  const int tid = threadIdx.x;
  const int w = tid >> 6, l = tid & 63;
  const int l15 = l & 15, l4 = l >> 4;
  const int qt = z * 4 + w;                       // 0..15 (16-row tile index)
  __shared__ ushort_t P[4][16 * 64];

  const int qrow0 = seg * SEGLEN + qt * 16;
  bf16x8 aq[2];
#pragma unroll
  for (int kk = 0; kk < 2; ++kk)
    aq[kk] = *(const bf16x8*)(qr + ((size_t)h * N_TOK + qrow0 + l15) * HD + kk * 32 + l4 * 8);

  f32x4 o[4] = {};
  float m_run[4], l_run[4];
#pragma unroll
  for (int r = 0; r < 4; ++r) { m_run[r] = -1e30f; l_run[r] = 0.f; }

  const int kbmax = z;                            // qt>>2 == z for all 4 waves
  for (int kb = 0; kb <= kbmax; ++kb) {
    bf16x8 bk[4][2];
#pragma unroll
    for (int ni = 0; ni < 4; ++ni)
#pragma unroll
      for (int kk = 0; kk < 2; ++kk)
        bk[ni][kk] = *(const bf16x8*)(kr + ((size_t)h * N_TOK + seg * SEGLEN + kb * 64 + ni * 16 + l15) * HD + kk * 32 + l4 * 8);
    f32x4 s[4] = {};
#pragma unroll
    for (int ni = 0; ni < 4; ++ni)
#pragma unroll
      for (int kk = 0; kk < 2; ++kk)
        s[ni] = __builtin_amdgcn_mfma_f32_16x16x32_bf16(aq[kk], bk[ni][kk], s[ni], 0, 0, 0);

    const bool diag = (kb == kbmax);
#pragma unroll
    for (int ni = 0; ni < 4; ++ni)
#pragma unroll
      for (int r = 0; r < 4; ++r) {
        float v = s[ni][r] * 0.125f;
        if (diag) {
          const int qrow = qt * 16 + l4 * 4 + r;
          const int jcol = kb * 64 + ni * 16 + l15;
          if (jcol > qrow) v = -1e30f;
        }
        s[ni][r] = v;
      }

    float sc_[4];
#pragma unroll
    for (int r = 0; r < 4; ++r) {
      float pm = fmaxf(fmaxf(s[0][r], s[1][r]), fmaxf(s[2][r], s[3][r]));
      pm = fmaxf(pm, __shfl_xor(pm, 1));
      pm = fmaxf(pm, __shfl_xor(pm, 2));
      pm = fmaxf(pm, __shfl_xor(pm, 4));
      pm = fmaxf(pm, __shfl_xor(pm, 8));
      const float mn = fmaxf(m_run[r], pm);
      sc_[r] = __expf(m_run[r] - mn);
      m_run[r] = mn;
    }
#pragma unroll
    for (int ni = 0; ni < 4; ++ni)
#pragma unroll
      for (int r = 0; r < 4; ++r)
        s[ni][r] = __expf(s[ni][r] - m_run[r]);
#pragma unroll
    for (int r = 0; r < 4; ++r) {
      float ls = s[0][r] + s[1][r] + s[2][r] + s[3][r];
      ls += __shfl_xor(ls, 1);
      ls += __shfl_xor(ls, 2);
      ls += __shfl_xor(ls, 4);
      ls += __shfl_xor(ls, 8);
      l_run[r] = l_run[r] * sc_[r] + ls;
    }
#pragma unroll
    for (int ni = 0; ni < 4; ++ni)
#pragma unroll
      for (int r = 0; r < 4; ++r)
        o[ni][r] *= sc_[r];

#pragma unroll
    for (int ni = 0; ni < 4; ++ni)
#pragma unroll
      for (int r = 0; r < 4; ++r)
        P[w][(l4 * 4 + r) * 64 + ni * 16 + l15] = f2bf(s[ni][r]);

    bf16x8 pa[2], bv[4][2];
#pragma unroll
    for (int k2 = 0; k2 < 2; ++k2)
      pa[k2] = *(const bf16x8*)(&P[w][l15 * 64 + k2 * 32 + l4 * 8]);
#pragma unroll
    for (int ni = 0; ni < 4; ++ni)
#pragma unroll
      for (int k2 = 0; k2 < 2; ++k2)
        bv[ni][k2] = *(const bf16x8*)(vT + ((size_t)h * HD + ni * 16 + l15) * N_TOK + seg * SEGLEN + kb * 64 + k2 * 32 + l4 * 8);
#pragma unroll
    for (int ni = 0; ni < 4; ++ni)
#pragma unroll
      for (int k2 = 0; k2 < 2; ++k2)
        o[ni] = __builtin_amdgcn_mfma_f32_16x16x32_bf16(pa[k2], bv[ni][k2], o[ni], 0, 0, 0);
  }

#pragma unroll
  for (int ni = 0; ni < 4; ++ni)
#pragma unroll
    for (int r = 0; r < 4; ++r) {
      const int row = qrow0 + l4 * 4 + r;
      const int col = h * HD + ni * 16 + l15;
      ab[(size_t)row * ABCOLS + col] = f2bf(o[ni][r] / l_run[r]);
    }
}

// ---------------------------------------------------------------- silu gate (bf16 t, x8)
__global__ __launch_bounds__(256) void silu_kernel(const ushort_t* __restrict__ t,
                                                   ushort_t* __restrict__ ab) {
  const int idx = blockIdx.x * 256 + threadIdx.x;
  const int n = idx / 384;                 // 3072/8 groups per row
  const int c = (idx - n * 384) * 8;
  const u16x8 v1 = *(const u16x8*)(t + (size_t)n * TCOLS + c);
  const u16x8 v2 = *(const u16x8*)(t + (size_t)n * TCOLS + FFI + c);
  u16x8 o;
#pragma unroll
  for (int j = 0; j < 8; ++j) {
    const float x1 = bf2f(v1[j]), x2 = bf2f(v2[j]);
    o[j] = f2bf(x1 / (1.f + __expf(-x1)) * x2);
  }
  *(u16x8*)(ab + (size_t)n * ABCOLS + HDIM + c) = o;
}

// ----------------------------------------------------------------
extern "C" void kernel_launch(void* const* d_in, const int* in_sizes, int n_in,
                              void* d_out, int out_size, void* d_ws, size_t ws_size,
                              hipStream_t stream) {
  const int*   tokens   = (const int*)d_in[0];
  const float* ages     = (const float*)d_in[1];
  const float* time_d   = (const float*)d_in[2];
  const float* embed    = (const float*)d_in[4];
  const float* in_nw    = (const float*)d_in[5];
  const float* out_nw   = (const float*)d_in[6];
  const float* layer_nw = (const float*)d_in[7];
  const float* Win      = (const float*)d_in[8];
  const float* Wout     = (const float*)d_in[9];
  float* out = (float*)d_out;

  char* ws = (char*)d_ws;
  float*    x      = (float*)   (ws + 0);            //  6,291,456
  ushort_t* hbuf   = (ushort_t*)(ws + 6291456);      //  3,145,728
  float*    sintab = (float*)   (ws + 9437184);      //    524,288
  float*    costab = (float*)   (ws + 9961472);      //    524,288
  ushort_t* tbuf   = (ushort_t*)(ws + 10485760);     // 34,603,008 (bf16)
  float*    cpart  = (float*)   (ws + 45088768);     // 31,457,280 (5 slices)
  ushort_t* ab     = (ushort_t*)(ws + 79691776);     // 15,728,640
  ushort_t* qrb    = (ushort_t*)(ws + 95420416);     //  3,145,728
  ushort_t* krb    = (ushort_t*)(ws + 98566144);     //  3,145,728
  ushort_t* vTb    = (ushort_t*)(ws + 101711872);    //  3,145,728
  ushort_t* winT   = (ushort_t*)(ws + 104857600);    // 25,952,256
  ushort_t* woutT  = (ushort_t*)(ws + 130809856);    // 11,796,480  (end 142,606,336)

  transpose_convert<<<dim3(TCOLS / 32, HDIM / 32, 2), dim3(32, 8), 0, stream>>>(Win, winT, HDIM, TCOLS);
  transpose_convert<<<dim3(HDIM / 32, ABCOLS / 32, 2), dim3(32, 8), 0, stream>>>(Wout, woutT, ABCOLS, HDIM);
  sincos_kernel<<<dim3(N_TOK / 8), dim3(256), 0, stream>>>(ages, sintab, costab);
  rms_kernel<<<dim3(N_TOK), dim3(256), 0, stream>>>(embed, tokens, in_nw, nullptr, x, nullptr, 0);
  rms_kernel<<<dim3(N_TOK), dim3(256), 0, stream>>>(x, nullptr, layer_nw, time_d,
                                                    nullptr, hbuf, 1);

  for (int lyr = 0; lyr < 2; ++lyr) {
    gemm1z<<<dim3(768), dim3(256), 0, stream>>>(hbuf, winT + (size_t)lyr * TCOLS * HDIM, tbuf);
    extract_kernel<<<dim3(N_TOK / 64, NHEADS), dim3(256), 0, stream>>>(tbuf, sintab, costab,
                                                                       qrb, krb, vTb);
    attn_kernel<<<dim3(NHEADS, NSEG, 4), dim3(256), 0, stream>>>(qrb, krb, vTb, ab);
    silu_kernel<<<dim3(N_TOK * FFI / 8 / 256), dim3(256), 0, stream>>>(tbuf, ab);
    gemm2_splitk<<<dim3(HDIM / 128, N_TOK / 128, KSPLIT), dim3(256), 0, stream>>>(
        ab, woutT + (size_t)lyr * HDIM * ABCOLS, cpart);
    if (lyr == 0)
      rms_fused<<<dim3(N_TOK), dim3(256), 0, stream>>>(cpart, x, layer_nw + HDIM, time_d,
                                                       nullptr, hbuf, 1);
    else
      rms_fused<<<dim3(N_TOK), dim3(256), 0, stream>>>(cpart, x, out_nw, nullptr,
                                                       out, nullptr, 2);
  }
}

// Round 6
// 206.962 us; speedup vs baseline: 1.0935x; 1.0935x over previous
//
#include <hip/hip_runtime.h>
#include <math.h>

typedef unsigned short ushort_t;
typedef float f32x4 __attribute__((ext_vector_type(4)));
typedef __bf16 bf16x8 __attribute__((ext_vector_type(8)));
typedef ushort_t u16x8 __attribute__((ext_vector_type(8)));

#define DEVFN __device__ __forceinline__

DEVFN ushort_t f2bf(float f) {
  unsigned int u = __float_as_uint(f);
  u += 0x7FFFu + ((u >> 16) & 1u);   // round-to-nearest-even
  return (ushort_t)(u >> 16);
}
DEVFN float bf2f(ushort_t u) { return __uint_as_float((unsigned int)u << 16); }

DEVFN void gload(const ushort_t* src, char* dst) {
  __builtin_amdgcn_global_load_lds(
      (const __attribute__((address_space(1))) unsigned int*)src,
      (__attribute__((address_space(3))) unsigned int*)dst, 16, 0, 0);
}

#define N_TOK  2048
#define HDIM   768
#define TCOLS  8448     // 2*I + 3*H
#define FFI    3072
#define NHEADS 12
#define HD     64
#define NSEG   8
#define SEGLEN 256
#define ABCOLS 3840     // H + I
#define KSPLIT 5
#define KCHUNK 768      // 3840 / 5

// ---------------------------------------------------------------- merged weight transpose+convert
// Win: 2 x [768 x 8448] -> winT 2 x [8448 x 768]; Wout: 2 x [3840 x 768] -> woutT 2 x [768 x 3840]
__global__ void transpose_all(const float* __restrict__ Win, const float* __restrict__ Wout,
                              ushort_t* __restrict__ winT, ushort_t* __restrict__ woutT) {
  __shared__ ushort_t tile[32][33];
  int id = blockIdx.x;
  const float* in; ushort_t* out; int R, C, tr, tc;
  if (id < 12672) {                       // Win: 264 col-tiles x 24 row-tiles x 2
    const int z = id / 6336; id -= z * 6336;
    R = HDIM; C = TCOLS;
    tc = (id % 264) * 32; tr = (id / 264) * 32;
    in = Win + (size_t)z * R * C; out = winT + (size_t)z * R * C;
  } else {                                // Wout: 24 col-tiles x 120 row-tiles x 2
    id -= 12672;
    const int z = id / 2880; id -= z * 2880;
    R = ABCOLS; C = HDIM;
    tc = (id % 24) * 32; tr = (id / 24) * 32;
    in = Wout + (size_t)z * R * C; out = woutT + (size_t)z * R * C;
  }
  const int tx = threadIdx.x, ty = threadIdx.y;   // 32 x 8
#pragma unroll
  for (int i = 0; i < 4; ++i)
    tile[ty + i * 8][tx] = f2bf(in[(size_t)(tr + ty + i * 8) * C + tc + tx]);
  __syncthreads();
#pragma unroll
  for (int i = 0; i < 4; ++i)
    out[(size_t)(tc + ty + i * 8) * R + tr + tx] = tile[tx][ty + i * 8];
}

// ---------------------------------------------------------------- rope table: float2 {cos, sin}
__global__ __launch_bounds__(256) void sincos_kernel(const float* __restrict__ ages,
                                                     float2* __restrict__ sctab) {
  const int n = blockIdx.x * 8 + (threadIdx.x >> 5), k = threadIdx.x & 31;
  const float e = (2.0f * (float)k) / 31.0f;
  const float inv = expf(-e * logf(10000.0f));
  const float t = ages[n] * inv;
  float2 cs; cs.x = cosf(t); cs.y = sinf(t);
  sctab[n * HD + 2 * k] = cs;
  sctab[n * HD + 2 * k + 1] = cs;
}

// ---------------------------------------------------------------- fused embed-gather + rms + rms
// x = rmsnorm(embed[tok], in_nw); hbuf = bf16(rmsnorm(x, layer_nw0) with time override)
__global__ __launch_bounds__(256) void rms_init(
    const float* __restrict__ embed, const int* __restrict__ tokens,
    const float* __restrict__ in_nw, const float* __restrict__ layer_nw,
    const float* __restrict__ time_data,
    float* __restrict__ x, ushort_t* __restrict__ hbuf) {
  const int row = blockIdx.x;
  const float* src = embed + (size_t)tokens[row] * HDIM;
  __shared__ float part[4];
  float v[3]; float ss = 0.f;
#pragma unroll
  for (int i = 0; i < 3; ++i) { v[i] = src[threadIdx.x + i * 256]; ss += v[i] * v[i]; }
#pragma unroll
  for (int off = 1; off < 64; off <<= 1) ss += __shfl_xor(ss, off);
  if ((threadIdx.x & 63) == 0) part[threadIdx.x >> 6] = ss;
  __syncthreads();
  const float rs = rsqrtf((part[0] + part[1] + part[2] + part[3]) * (1.0f / HDIM) + 1e-6f);
  float y[3]; float ss2 = 0.f;
#pragma unroll
  for (int i = 0; i < 3; ++i) {
    const int c = threadIdx.x + i * 256;
    y[i] = v[i] * rs * in_nw[c];
    x[(size_t)row * HDIM + c] = y[i];
    ss2 += y[i] * y[i];
  }
#pragma unroll
  for (int off = 1; off < 64; off <<= 1) ss2 += __shfl_xor(ss2, off);
  __syncthreads();
  if ((threadIdx.x & 63) == 0) part[threadIdx.x >> 6] = ss2;
  __syncthreads();
  const float rs2 = rsqrtf((part[0] + part[1] + part[2] + part[3]) * (1.0f / HDIM) + 1e-6f);
#pragma unroll
  for (int i = 0; i < 3; ++i) {
    const int c = threadIdx.x + i * 256;
    float val = y[i] * rs2 * layer_nw[c];
    if (c >= HDIM - 4) {
      const float td = time_data[row * 2 + (c & 1)];
      val = (c >= HDIM - 2) ? td * td : td;
    }
    hbuf[(size_t)row * HDIM + c] = f2bf(val);
  }
}

// ---------------------------------------------------------------- fused splitK-reduce + residual + rmsnorm
__global__ __launch_bounds__(256) void rms_fused(
    const float* __restrict__ cpart, float* __restrict__ x,
    const float* __restrict__ w, const float* __restrict__ time_data,
    float* __restrict__ out_f32, ushort_t* __restrict__ out_bf16, const int mode) {
  const int row = blockIdx.x;
  const size_t stride = (size_t)N_TOK * HDIM;
  float v[3]; float ss = 0.f;
#pragma unroll
  for (int i = 0; i < 3; ++i) {
    const size_t idx = (size_t)row * HDIM + threadIdx.x + i * 256;
    float s = x[idx];
#pragma unroll
    for (int z = 0; z < KSPLIT; ++z) s += cpart[z * stride + idx];
    if (mode == 1) x[idx] = s;
    v[i] = s; ss += s * s;
  }
#pragma unroll
  for (int off = 1; off < 64; off <<= 1) ss += __shfl_xor(ss, off);
  __shared__ float part[4];
  if ((threadIdx.x & 63) == 0) part[threadIdx.x >> 6] = ss;
  __syncthreads();
  const float rs = rsqrtf((part[0] + part[1] + part[2] + part[3]) * (1.0f / HDIM) + 1e-6f);
#pragma unroll
  for (int i = 0; i < 3; ++i) {
    const int c = threadIdx.x + i * 256;
    float val = v[i] * rs * w[c];
    if (mode == 1) {
      if (c >= HDIM - 4) {
        const float td = time_data[row * 2 + (c & 1)];
        val = (c >= HDIM - 2) ? td * td : td;
      }
      out_bf16[(size_t)row * HDIM + c] = f2bf(val);
    } else {
      out_f32[(size_t)row * HDIM + c] = val;
    }
  }
}

// ---------------------------------------------------------------- GEMM1 fused: 128x192, BK=32, 704 blocks
// Virtual B-row space: ff cols [0,6144) interleaved x1/x2 in 16-col blocks (silu pairs in-lane);
// qkv cols [6144,8448) identity. Epilogue: silu->ab, rope->qr/kr, transpose->vT.
#define G1_NT 24
#define G1_ABYT 8192          // 128x32 bf16
#define G1_BUF  20480         // + 192x32 bf16 (12288)

DEVFN int swz64(int p) {      // 64B rows: slot bits 4-5 ^= rowbits(0-1)^rowbits(2-3)
  const int g = ((p >> 6) & 3) ^ ((p >> 8) & 3);
  return p ^ (g << 4);
}
DEVFN int ffmap(int vr) {     // virtual B row -> real W_in column
  return (vr < 2 * FFI) ? ((((vr >> 4) & 1) * FFI) + ((vr >> 5) << 4) + (vr & 15)) : vr;
}

DEVFN void g1f_stage(const ushort_t* __restrict__ A, const ushort_t* __restrict__ BT,
                     int m0, int n0, int kt_el, char* buf, int tid) {
#pragma unroll
  for (int i = 0; i < 2; ++i) {       // A: 8KB
    const int q = swz64(i * 4096 + tid * 16);
    gload(A + (size_t)(m0 + (q >> 6)) * HDIM + kt_el + ((q & 63) >> 1),
          buf + i * 4096 + ((tid >> 6) << 10));
  }
#pragma unroll
  for (int i = 0; i < 3; ++i) {       // B: 12KB (192 virtual rows)
    const int q = swz64(i * 4096 + tid * 16);
    const int vr = n0 + (q >> 6);
    gload(BT + (size_t)ffmap(vr) * HDIM + kt_el + ((q & 63) >> 1),
          buf + G1_ABYT + i * 4096 + ((tid >> 6) << 10));
  }
}

__global__ __launch_bounds__(256, 3) void gemm1f(
    const ushort_t* __restrict__ A, const ushort_t* __restrict__ BT,
    const float2* __restrict__ sctab,
    ushort_t* __restrict__ ab, ushort_t* __restrict__ qr,
    ushort_t* __restrict__ kr, ushort_t* __restrict__ vT) {
  __shared__ __align__(16) char smem[2 * G1_BUF];     // 40 KiB
  const int tid = threadIdx.x;
  const int l = tid & 63, l15 = l & 15, l4 = l >> 4;
  const int wid = tid >> 6, wr = wid >> 1, wc = wid & 1;   // 2x2 waves
  const int bid = (int)blockIdx.x;
  const int wg = (bid & 7) * 88 + (bid >> 3);         // XCD-contiguous
  const int nt = wg >> 4, mt = wg & 15;               // 44 N-tiles x 16 M-tiles
  const int m0 = mt * 128, n0 = nt * 192;

  f32x4 acc[4][6] = {};

  g1f_stage(A, BT, m0, n0, 0,  smem, tid);
  g1f_stage(A, BT, m0, n0, 32, smem + G1_BUF, tid);
  asm volatile("s_waitcnt vmcnt(5)" ::: "memory");    // tile 0 landed
  __builtin_amdgcn_s_barrier();
  __builtin_amdgcn_sched_barrier(0);

  for (int t = 0; t < G1_NT; ++t) {
    const char* bufA = smem + (t & 1) * G1_BUF;
    const char* bufB = bufA + G1_ABYT;
    bf16x8 a4[4], b6[6];
#pragma unroll
    for (int m = 0; m < 4; ++m) {
      const int p = (wr * 64 + m * 16 + l15) * 64 + l4 * 16;
      a4[m] = *(const bf16x8*)(bufA + swz64(p));
    }
#pragma unroll
    for (int n = 0; n < 6; ++n) {
      const int p = (wc * 96 + n * 16 + l15) * 64 + l4 * 16;
      b6[n] = *(const bf16x8*)(bufB + swz64(p));
    }
#pragma unroll
    for (int m = 0; m < 4; ++m)
#pragma unroll
      for (int n = 0; n < 6; ++n)
        acc[m][n] = __builtin_amdgcn_mfma_f32_16x16x32_bf16(a4[m], b6[n], acc[m][n], 0, 0, 0);

    if (t == G1_NT - 1) break;
    __builtin_amdgcn_sched_barrier(0);
    __builtin_amdgcn_s_barrier();                     // reads of buf[t&1] done
    if (t + 2 < G1_NT) {
      g1f_stage(A, BT, m0, n0, (t + 2) * 32, smem + (t & 1) * G1_BUF, tid);
      asm volatile("s_waitcnt vmcnt(5)" ::: "memory"); // tile t+1 landed
    } else {
      asm volatile("s_waitcnt vmcnt(0)" ::: "memory");
    }
    __builtin_amdgcn_s_barrier();
    __builtin_amdgcn_sched_barrier(0);
  }

  if (nt < 32) {
    // ---- ff tiles: silu(x1)*x2 -> ab cols [768, 3840)
#pragma unroll
    for (int m = 0; m < 4; ++m)
#pragma unroll
      for (int np = 0; np < 3; ++np) {
        const int colj = (nt * 6 + wc * 3 + np) * 16 + l15;   // [0, 3072)
#pragma unroll
        for (int r = 0; r < 4; ++r) {
          const float x1 = acc[m][2 * np][r], x2 = acc[m][2 * np + 1][r];
          const float sv = x1 / (1.f + __expf(-x1)) * x2;
          const int row = m0 + wr * 64 + m * 16 + l4 * 4 + r;
          ab[(size_t)row * ABCOLS + HDIM + colj] = f2bf(sv);
        }
      }
  } else {
    // ---- qkv tiles: rope q/k, transpose v
#pragma unroll
    for (int n = 0; n < 6; ++n) {
      const int gcol = (nt - 32) * 192 + wc * 96 + n * 16;    // [0, 2304)
      const int g = gcol >> 6;                                // qkv*12 + h
      const int typ = g / NHEADS, h = g - typ * NHEADS;
      const int d = (gcol & 63) + l15;
      if (typ == 2) {
#pragma unroll
        for (int m = 0; m < 4; ++m) {
          ushort4 pk;
          pk.x = f2bf(acc[m][n][0]); pk.y = f2bf(acc[m][n][1]);
          pk.z = f2bf(acc[m][n][2]); pk.w = f2bf(acc[m][n][3]);
          const int row0 = m0 + wr * 64 + m * 16 + l4 * 4;
          *(ushort4*)(vT + ((size_t)h * HD + d) * N_TOK + row0) = pk;
        }
      } else {
        ushort_t* dst = (typ == 0) ? qr : kr;
        const float sgn = (l15 & 1) ? 1.f : -1.f;
#pragma unroll
        for (int m = 0; m < 4; ++m)
#pragma unroll
          for (int r = 0; r < 4; ++r) {
            const float val = acc[m][n][r];
            const float partner = __shfl_xor(val, 1);
            const int row = m0 + wr * 64 + m * 16 + l4 * 4 + r;
            const float2 cs = sctab[row * HD + d];
            dst[((size_t)h * N_TOK + row) * HD + d] = f2bf(val * cs.x + sgn * partner * cs.y);
          }
      }
    }
  }
}

// ---------------------------------------------------------------- GEMM2: 128x128 split-K, pipelined
#define G2_NT 12              // KCHUNK / 64
#define G2_BUF 32768          // A 16KB + B 16KB

DEVFN int swz128(int p) { return p ^ (((p >> 7) & 7) << 4); }   // 128B rows

DEVFN void g2_stage(const ushort_t* __restrict__ A, const ushort_t* __restrict__ BT,
                    int m0, int n0, int kt_el, char* buf, int tid) {
#pragma unroll
  for (int i = 0; i < 8; ++i) {
    const int p = i * 4096 + tid * 16;
    const bool isA = p < 16384;
    const int q = swz128(isA ? p : p - 16384);
    const int row = q >> 7, colel = (q & 127) >> 1;
    const ushort_t* src = (isA ? A + (size_t)(m0 + row) * ABCOLS
                               : BT + (size_t)(n0 + row) * ABCOLS) + kt_el + colel;
    gload(src, buf + i * 4096 + ((tid >> 6) << 10));
  }
}

__global__ __launch_bounds__(256, 2) void gemm2_splitk(
    const ushort_t* __restrict__ A, const ushort_t* __restrict__ BT,
    float* __restrict__ Cp) {
  __shared__ __align__(16) char smem[2 * G2_BUF];     // 64 KiB
  const int tid = threadIdx.x;
  const int l = tid & 63, l15 = l & 15, l4 = l >> 4;
  const int w = tid >> 6, wr = w >> 1, wc = w & 1;
  const int m0 = blockIdx.y * 128, n0 = blockIdx.x * 128;
  const int kt0 = blockIdx.z * KCHUNK;

  f32x4 acc[4][4] = {};

  g2_stage(A, BT, m0, n0, kt0, smem, tid);
  g2_stage(A, BT, m0, n0, kt0 + 64, smem + G2_BUF, tid);
  asm volatile("s_waitcnt vmcnt(8)" ::: "memory");
  __builtin_amdgcn_s_barrier();
  __builtin_amdgcn_sched_barrier(0);

  for (int t = 0; t < G2_NT; ++t) {
    const char* bufA = smem + (t & 1) * G2_BUF;
    const char* bufB = bufA + 16384;
    bf16x8 af[4][2], bv[4][2];
#pragma unroll
    for (int kk = 0; kk < 2; ++kk) {
#pragma unroll
      for (int mi = 0; mi < 4; ++mi) {
        const int p = (wr * 64 + mi * 16 + l15) * 128 + kk * 64 + l4 * 16;
        af[mi][kk] = *(const bf16x8*)(bufA + swz128(p));
      }
#pragma unroll
      for (int ni = 0; ni < 4; ++ni) {
        const int p = (wc * 64 + ni * 16 + l15) * 128 + kk * 64 + l4 * 16;
        bv[ni][kk] = *(const bf16x8*)(bufB + swz128(p));
      }
    }
#pragma unroll
    for (int kk = 0; kk < 2; ++kk)
#pragma unroll
      for (int mi = 0; mi < 4; ++mi)
#pragma unroll
        for (int ni = 0; ni < 4; ++ni)
          acc[mi][ni] = __builtin_amdgcn_mfma_f32_16x16x32_bf16(af[mi][kk], bv[ni][kk], acc[mi][ni], 0, 0, 0);

    if (t == G2_NT - 1) break;
    __builtin_amdgcn_sched_barrier(0);
    __builtin_amdgcn_s_barrier();
    if (t + 2 < G2_NT) {
      g2_stage(A, BT, m0, n0, kt0 + (t + 2) * 64, smem + (t & 1) * G2_BUF, tid);
      asm volatile("s_waitcnt vmcnt(8)" ::: "memory");
    } else {
      asm volatile("s_waitcnt vmcnt(0)" ::: "memory");
    }
    __builtin_amdgcn_s_barrier();
    __builtin_amdgcn_sched_barrier(0);
  }

  float* Cz = Cp + (size_t)blockIdx.z * N_TOK * HDIM;
#pragma unroll
  for (int mi = 0; mi < 4; ++mi)
#pragma unroll
    for (int ni = 0; ni < 4; ++ni)
#pragma unroll
      for (int r = 0; r < 4; ++r) {
        const int row = m0 + wr * 64 + mi * 16 + l4 * 4 + r;
        const int col = n0 + wc * 64 + ni * 16 + l15;
        Cz[(size_t)row * HDIM + col] = acc[mi][ni][r];
      }
}

// ---------------------------------------------------------------- segment attention, 16-row q-tiles
__global__ __launch_bounds__(256) void attn_kernel(
    const ushort_t* __restrict__ qr, const ushort_t* __restrict__ kr,
    const ushort_t* __restrict__ vT, ushort_t* __restrict__ ab) {
  const int h = blockIdx.x, seg = blockIdx.y, z = blockIdx.z;
  const int tid = threadIdx.x;
  const int w = tid >> 6, l = tid & 63;
  const int l15 = l & 15, l4 = l >> 4;
  const int qt = z * 4 + w;                       // 0..15
  __shared__ ushort_t P[4][16 * 64];

  const int qrow0 = seg * SEGLEN + qt * 16;
  bf16x8 aq[2];
#pragma unroll
  for (int kk = 0; kk < 2; ++kk)
    aq[kk] = *(const bf16x8*)(qr + ((size_t)h * N_TOK + qrow0 + l15) * HD + kk * 32 + l4 * 8);

  f32x4 o[4] = {};
  float m_run[4], l_run[4];
#pragma unroll
  for (int r = 0; r < 4; ++r) { m_run[r] = -1e30f; l_run[r] = 0.f; }

  const int kbmax = z;
  for (int kb = 0; kb <= kbmax; ++kb) {
    bf16x8 bk[4][2];
#pragma unroll
    for (int ni = 0; ni < 4; ++ni)
#pragma unroll
      for (int kk = 0; kk < 2; ++kk)
        bk[ni][kk] = *(const bf16x8*)(kr + ((size_t)h * N_TOK + seg * SEGLEN + kb * 64 + ni * 16 + l15) * HD + kk * 32 + l4 * 8);
    f32x4 s[4] = {};
#pragma unroll
    for (int ni = 0; ni < 4; ++ni)
#pragma unroll
      for (int kk = 0; kk < 2; ++kk)
        s[ni] = __builtin_amdgcn_mfma_f32_16x16x32_bf16(aq[kk], bk[ni][kk], s[ni], 0, 0, 0);

    const bool diag = (kb == kbmax);
#pragma unroll
    for (int ni = 0; ni < 4; ++ni)
#pragma unroll
      for (int r = 0; r < 4; ++r) {
        float v = s[ni][r] * 0.125f;
        if (diag) {
          const int qrow = qt * 16 + l4 * 4 + r;
          const int jcol = kb * 64 + ni * 16 + l15;
          if (jcol > qrow) v = -1e30f;
        }
        s[ni][r] = v;
      }

    float sc_[4];
#pragma unroll
    for (int r = 0; r < 4; ++r) {
      float pm = fmaxf(fmaxf(s[0][r], s[1][r]), fmaxf(s[2][r], s[3][r]));
      pm = fmaxf(pm, __shfl_xor(pm, 1));
      pm = fmaxf(pm, __shfl_xor(pm, 2));
      pm = fmaxf(pm, __shfl_xor(pm, 4));
      pm = fmaxf(pm, __shfl_xor(pm, 8));
      const float mn = fmaxf(m_run[r], pm);
      sc_[r] = __expf(m_run[r] - mn);
      m_run[r] = mn;
    }
#pragma unroll
    for (int ni = 0; ni < 4; ++ni)
#pragma unroll
      for (int r = 0; r < 4; ++r)
        s[ni][r] = __expf(s[ni][r] - m_run[r]);
#pragma unroll
    for (int r = 0; r < 4; ++r) {
      float ls = s[0][r] + s[1][r] + s[2][r] + s[3][r];
      ls += __shfl_xor(ls, 1);
      ls += __shfl_xor(ls, 2);
      ls += __shfl_xor(ls, 4);
      ls += __shfl_xor(ls, 8);
      l_run[r] = l_run[r] * sc_[r] + ls;
    }
#pragma unroll
    for (int ni = 0; ni < 4; ++ni)
#pragma unroll
      for (int r = 0; r < 4; ++r)
        o[ni][r] *= sc_[r];

#pragma unroll
    for (int ni = 0; ni < 4; ++ni)
#pragma unroll
      for (int r = 0; r < 4; ++r)
        P[w][(l4 * 4 + r) * 64 + ni * 16 + l15] = f2bf(s[ni][r]);

    bf16x8 pa[2], bv[4][2];
#pragma unroll
    for (int k2 = 0; k2 < 2; ++k2)
      pa[k2] = *(const bf16x8*)(&P[w][l15 * 64 + k2 * 32 + l4 * 8]);
#pragma unroll
    for (int ni = 0; ni < 4; ++ni)
#pragma unroll
      for (int k2 = 0; k2 < 2; ++k2)
        bv[ni][k2] = *(const bf16x8*)(vT + ((size_t)h * HD + ni * 16 + l15) * N_TOK + seg * SEGLEN + kb * 64 + k2 * 32 + l4 * 8);
#pragma unroll
    for (int ni = 0; ni < 4; ++ni)
#pragma unroll
      for (int k2 = 0; k2 < 2; ++k2)
        o[ni] = __builtin_amdgcn_mfma_f32_16x16x32_bf16(pa[k2], bv[ni][k2], o[ni], 0, 0, 0);
  }

#pragma unroll
  for (int ni = 0; ni < 4; ++ni)
#pragma unroll
    for (int r = 0; r < 4; ++r) {
      const int row = qrow0 + l4 * 4 + r;
      const int col = h * HD + ni * 16 + l15;
      ab[(size_t)row * ABCOLS + col] = f2bf(o[ni][r] / l_run[r]);
    }
}

// ----------------------------------------------------------------
extern "C" void kernel_launch(void* const* d_in, const int* in_sizes, int n_in,
                              void* d_out, int out_size, void* d_ws, size_t ws_size,
                              hipStream_t stream) {
  const int*   tokens   = (const int*)d_in[0];
  const float* ages     = (const float*)d_in[1];
  const float* time_d   = (const float*)d_in[2];
  const float* embed    = (const float*)d_in[4];
  const float* in_nw    = (const float*)d_in[5];
  const float* out_nw   = (const float*)d_in[6];
  const float* layer_nw = (const float*)d_in[7];
  const float* Win      = (const float*)d_in[8];
  const float* Wout     = (const float*)d_in[9];
  float* out = (float*)d_out;

  char* ws = (char*)d_ws;
  float*    x      = (float*)   (ws + 0);            //  6,291,456
  ushort_t* hbuf   = (ushort_t*)(ws + 6291456);      //  3,145,728
  float2*   sctab  = (float2*)  (ws + 9437184);      //  1,048,576
  float*    cpart  = (float*)   (ws + 10485760);     // 31,457,280
  ushort_t* ab     = (ushort_t*)(ws + 41943040);     // 15,728,640
  ushort_t* qrb    = (ushort_t*)(ws + 57671680);     //  3,145,728
  ushort_t* krb    = (ushort_t*)(ws + 60817408);     //  3,145,728
  ushort_t* vTb    = (ushort_t*)(ws + 63963136);     //  3,145,728
  ushort_t* winT   = (ushort_t*)(ws + 67108864);     // 25,952,256
  ushort_t* woutT  = (ushort_t*)(ws + 93061120);     // 11,796,480  (end 104,857,600)

  transpose_all<<<dim3(18432), dim3(32, 8), 0, stream>>>(Win, Wout, winT, woutT);
  sincos_kernel<<<dim3(N_TOK / 8), dim3(256), 0, stream>>>(ages, sctab);
  rms_init<<<dim3(N_TOK), dim3(256), 0, stream>>>(embed, tokens, in_nw, layer_nw, time_d,
                                                  x, hbuf);

  for (int lyr = 0; lyr < 2; ++lyr) {
    gemm1f<<<dim3(704), dim3(256), 0, stream>>>(hbuf, winT + (size_t)lyr * TCOLS * HDIM,
                                                sctab, ab, qrb, krb, vTb);
    attn_kernel<<<dim3(NHEADS, NSEG, 4), dim3(256), 0, stream>>>(qrb, krb, vTb, ab);
    gemm2_splitk<<<dim3(HDIM / 128, N_TOK / 128, KSPLIT), dim3(256), 0, stream>>>(
        ab, woutT + (size_t)lyr * HDIM * ABCOLS, cpart);
    if (lyr == 0)
      rms_fused<<<dim3(N_TOK), dim3(256), 0, stream>>>(cpart, x, layer_nw + HDIM, time_d,
                                                       nullptr, hbuf, 1);
    else
      rms_fused<<<dim3(N_TOK), dim3(256), 0, stream>>>(cpart, x, out_nw, nullptr,
                                                       out, nullptr, 2);
  }
}

// Round 7
// 186.524 us; speedup vs baseline: 1.2133x; 1.1096x over previous
//
#include <hip/hip_runtime.h>
#include <math.h>

typedef unsigned short ushort_t;
typedef float f32x4 __attribute__((ext_vector_type(4)));
typedef __bf16 bf16x8 __attribute__((ext_vector_type(8)));

#define DEVFN __device__ __forceinline__

DEVFN ushort_t f2bf(float f) {
  unsigned int u = __float_as_uint(f);
  u += 0x7FFFu + ((u >> 16) & 1u);   // round-to-nearest-even
  return (ushort_t)(u >> 16);
}
DEVFN float bf2f(ushort_t u) { return __uint_as_float((unsigned int)u << 16); }

DEVFN void gload(const ushort_t* src, char* dst) {
  __builtin_amdgcn_global_load_lds(
      (const __attribute__((address_space(1))) unsigned int*)src,
      (__attribute__((address_space(3))) unsigned int*)dst, 16, 0, 0);
}

#define N_TOK  2048
#define HDIM   768
#define TCOLS  8448     // 2*I + 3*H
#define FFI    3072
#define NHEADS 12
#define HD     64
#define NSEG   8
#define SEGLEN 256
#define ABCOLS 3840     // H + I
#define NPART  6        // 4 ff chunks (K=768 each) + 2 attn half-chunks (K=384)
#define KCHUNK 768

// ---------------------------------------------------------------- weight transpose+convert (64x32 tiles)
// Win: 2 x [768 x 8448] -> winT 2 x [8448 x 768]; Wout: 2 x [3840 x 768] -> woutT 2 x [768 x 3840]
__global__ __launch_bounds__(256) void transpose_all(
    const float* __restrict__ Win, const float* __restrict__ Wout,
    ushort_t* __restrict__ winT, ushort_t* __restrict__ woutT) {
  __shared__ ushort_t tile[32][66];
  int id = blockIdx.x;
  const float* in; ushort_t* out; int R, C, tr, tc;
  if (id < 6336) {                        // Win: 12 row-tiles x 264 col-tiles x 2
    const int z = id / 3168; id -= z * 3168;
    R = HDIM; C = TCOLS;
    tr = (id / 264) * 64; tc = (id % 264) * 32;
    in = Win + (size_t)z * R * C; out = winT + (size_t)z * R * C;
  } else {                                // Wout: 60 row-tiles x 24 col-tiles x 2
    id -= 6336;
    const int z = id / 1440; id -= z * 1440;
    R = ABCOLS; C = HDIM;
    tr = (id / 24) * 64; tc = (id % 24) * 32;
    in = Wout + (size_t)z * R * C; out = woutT + (size_t)z * R * C;
  }
  const int tx = threadIdx.x, ty = threadIdx.y;   // 32 x 8
#pragma unroll
  for (int i = 0; i < 8; ++i) {
    const int r = ty + i * 8;
    tile[tx][r] = f2bf(in[(size_t)(tr + r) * C + tc + tx]);
  }
  __syncthreads();
#pragma unroll
  for (int i = 0; i < 4; ++i) {
    const int c = ty + i * 8;
    ushort2 pk; pk.x = tile[c][2 * tx]; pk.y = tile[c][2 * tx + 1];
    *(ushort2*)(out + (size_t)(tc + c) * R + tr + 2 * tx) = pk;
  }
}

// ---------------------------------------------------------------- fused sincos + embed-gather + rms + rms
__global__ __launch_bounds__(256) void rms_init(
    const float* __restrict__ embed, const int* __restrict__ tokens,
    const float* __restrict__ ages,
    const float* __restrict__ in_nw, const float* __restrict__ layer_nw,
    const float* __restrict__ time_data,
    float* __restrict__ x, ushort_t* __restrict__ hbuf, float2* __restrict__ sctab) {
  const int row = blockIdx.x;
  if (threadIdx.x < 32) {                 // rope table for this row
    const int k = threadIdx.x;
    const float e = (2.0f * (float)k) / 31.0f;
    const float t = ages[row] * expf(-e * logf(10000.0f));
    float2 cs; cs.x = cosf(t); cs.y = sinf(t);
    sctab[row * HD + 2 * k] = cs;
    sctab[row * HD + 2 * k + 1] = cs;
  }
  const float* src = embed + (size_t)tokens[row] * HDIM;
  __shared__ float part[4];
  float v[3]; float ss = 0.f;
#pragma unroll
  for (int i = 0; i < 3; ++i) { v[i] = src[threadIdx.x + i * 256]; ss += v[i] * v[i]; }
#pragma unroll
  for (int off = 1; off < 64; off <<= 1) ss += __shfl_xor(ss, off);
  if ((threadIdx.x & 63) == 0) part[threadIdx.x >> 6] = ss;
  __syncthreads();
  const float rs = rsqrtf((part[0] + part[1] + part[2] + part[3]) * (1.0f / HDIM) + 1e-6f);
  float y[3]; float ss2 = 0.f;
#pragma unroll
  for (int i = 0; i < 3; ++i) {
    const int c = threadIdx.x + i * 256;
    y[i] = v[i] * rs * in_nw[c];
    x[(size_t)row * HDIM + c] = y[i];
    ss2 += y[i] * y[i];
  }
#pragma unroll
  for (int off = 1; off < 64; off <<= 1) ss2 += __shfl_xor(ss2, off);
  __syncthreads();
  if ((threadIdx.x & 63) == 0) part[threadIdx.x >> 6] = ss2;
  __syncthreads();
  const float rs2 = rsqrtf((part[0] + part[1] + part[2] + part[3]) * (1.0f / HDIM) + 1e-6f);
#pragma unroll
  for (int i = 0; i < 3; ++i) {
    const int c = threadIdx.x + i * 256;
    float val = y[i] * rs2 * layer_nw[c];
    if (c >= HDIM - 4) {
      const float td = time_data[row * 2 + (c & 1)];
      val = (c >= HDIM - 2) ? td * td : td;
    }
    hbuf[(size_t)row * HDIM + c] = f2bf(val);
  }
}

// ---------------------------------------------------------------- fused reduce(6 bf16 partials) + residual + rms
__global__ __launch_bounds__(256) void rms_fused(
    const ushort_t* __restrict__ cpartb, float* __restrict__ x,
    const float* __restrict__ w, const float* __restrict__ time_data,
    float* __restrict__ out_f32, ushort_t* __restrict__ out_bf16, const int mode) {
  const int row = blockIdx.x;
  const size_t stride = (size_t)N_TOK * HDIM;
  float v[3]; float ss = 0.f;
#pragma unroll
  for (int i = 0; i < 3; ++i) {
    const size_t idx = (size_t)row * HDIM + threadIdx.x + i * 256;
    float s = x[idx];
#pragma unroll
    for (int z = 0; z < NPART; ++z) s += bf2f(cpartb[z * stride + idx]);
    if (mode == 1) x[idx] = s;
    v[i] = s; ss += s * s;
  }
#pragma unroll
  for (int off = 1; off < 64; off <<= 1) ss += __shfl_xor(ss, off);
  __shared__ float part[4];
  if ((threadIdx.x & 63) == 0) part[threadIdx.x >> 6] = ss;
  __syncthreads();
  const float rs = rsqrtf((part[0] + part[1] + part[2] + part[3]) * (1.0f / HDIM) + 1e-6f);
#pragma unroll
  for (int i = 0; i < 3; ++i) {
    const int c = threadIdx.x + i * 256;
    float val = v[i] * rs * w[c];
    if (mode == 1) {
      if (c >= HDIM - 4) {
        const float td = time_data[row * 2 + (c & 1)];
        val = (c >= HDIM - 2) ? td * td : td;
      }
      out_bf16[(size_t)row * HDIM + c] = f2bf(val);
    } else {
      out_f32[(size_t)row * HDIM + c] = val;
    }
  }
}

// ---------------------------------------------------------------- GEMM1 fused (unchanged from r6)
#define G1_NT 24
#define G1_ABYT 8192
#define G1_BUF  20480

DEVFN int swz64(int p) {
  const int g = ((p >> 6) & 3) ^ ((p >> 8) & 3);
  return p ^ (g << 4);
}
DEVFN int ffmap(int vr) {
  return (vr < 2 * FFI) ? ((((vr >> 4) & 1) * FFI) + ((vr >> 5) << 4) + (vr & 15)) : vr;
}

DEVFN void g1f_stage(const ushort_t* __restrict__ A, const ushort_t* __restrict__ BT,
                     int m0, int n0, int kt_el, char* buf, int tid) {
#pragma unroll
  for (int i = 0; i < 2; ++i) {
    const int q = swz64(i * 4096 + tid * 16);
    gload(A + (size_t)(m0 + (q >> 6)) * HDIM + kt_el + ((q & 63) >> 1),
          buf + i * 4096 + ((tid >> 6) << 10));
  }
#pragma unroll
  for (int i = 0; i < 3; ++i) {
    const int q = swz64(i * 4096 + tid * 16);
    const int vr = n0 + (q >> 6);
    gload(BT + (size_t)ffmap(vr) * HDIM + kt_el + ((q & 63) >> 1),
          buf + G1_ABYT + i * 4096 + ((tid >> 6) << 10));
  }
}

__global__ __launch_bounds__(256, 3) void gemm1f(
    const ushort_t* __restrict__ A, const ushort_t* __restrict__ BT,
    const float2* __restrict__ sctab,
    ushort_t* __restrict__ ab, ushort_t* __restrict__ qr,
    ushort_t* __restrict__ kr, ushort_t* __restrict__ vT) {
  __shared__ __align__(16) char smem[2 * G1_BUF];
  const int tid = threadIdx.x;
  const int l = tid & 63, l15 = l & 15, l4 = l >> 4;
  const int wid = tid >> 6, wr = wid >> 1, wc = wid & 1;
  const int bid = (int)blockIdx.x;
  const int wg = (bid & 7) * 88 + (bid >> 3);
  const int nt = wg >> 4, mt = wg & 15;
  const int m0 = mt * 128, n0 = nt * 192;

  f32x4 acc[4][6] = {};

  g1f_stage(A, BT, m0, n0, 0,  smem, tid);
  g1f_stage(A, BT, m0, n0, 32, smem + G1_BUF, tid);
  asm volatile("s_waitcnt vmcnt(5)" ::: "memory");
  __builtin_amdgcn_s_barrier();
  __builtin_amdgcn_sched_barrier(0);

  for (int t = 0; t < G1_NT; ++t) {
    const char* bufA = smem + (t & 1) * G1_BUF;
    const char* bufB = bufA + G1_ABYT;
    bf16x8 a4[4], b6[6];
#pragma unroll
    for (int m = 0; m < 4; ++m) {
      const int p = (wr * 64 + m * 16 + l15) * 64 + l4 * 16;
      a4[m] = *(const bf16x8*)(bufA + swz64(p));
    }
#pragma unroll
    for (int n = 0; n < 6; ++n) {
      const int p = (wc * 96 + n * 16 + l15) * 64 + l4 * 16;
      b6[n] = *(const bf16x8*)(bufB + swz64(p));
    }
#pragma unroll
    for (int m = 0; m < 4; ++m)
#pragma unroll
      for (int n = 0; n < 6; ++n)
        acc[m][n] = __builtin_amdgcn_mfma_f32_16x16x32_bf16(a4[m], b6[n], acc[m][n], 0, 0, 0);

    if (t == G1_NT - 1) break;
    __builtin_amdgcn_sched_barrier(0);
    __builtin_amdgcn_s_barrier();
    if (t + 2 < G1_NT) {
      g1f_stage(A, BT, m0, n0, (t + 2) * 32, smem + (t & 1) * G1_BUF, tid);
      asm volatile("s_waitcnt vmcnt(5)" ::: "memory");
    } else {
      asm volatile("s_waitcnt vmcnt(0)" ::: "memory");
    }
    __builtin_amdgcn_s_barrier();
    __builtin_amdgcn_sched_barrier(0);
  }

  if (nt < 32) {
#pragma unroll
    for (int m = 0; m < 4; ++m)
#pragma unroll
      for (int np = 0; np < 3; ++np) {
        const int colj = (nt * 6 + wc * 3 + np) * 16 + l15;
#pragma unroll
        for (int r = 0; r < 4; ++r) {
          const float x1 = acc[m][2 * np][r], x2 = acc[m][2 * np + 1][r];
          const float sv = x1 / (1.f + __expf(-x1)) * x2;
          const int row = m0 + wr * 64 + m * 16 + l4 * 4 + r;
          ab[(size_t)row * ABCOLS + HDIM + colj] = f2bf(sv);
        }
      }
  } else {
#pragma unroll
    for (int n = 0; n < 6; ++n) {
      const int gcol = (nt - 32) * 192 + wc * 96 + n * 16;
      const int g = gcol >> 6;
      const int typ = g / NHEADS, h = g - typ * NHEADS;
      const int d = (gcol & 63) + l15;
      if (typ == 2) {
#pragma unroll
        for (int m = 0; m < 4; ++m) {
          ushort4 pk;
          pk.x = f2bf(acc[m][n][0]); pk.y = f2bf(acc[m][n][1]);
          pk.z = f2bf(acc[m][n][2]); pk.w = f2bf(acc[m][n][3]);
          const int row0 = m0 + wr * 64 + m * 16 + l4 * 4;
          *(ushort4*)(vT + ((size_t)h * HD + d) * N_TOK + row0) = pk;
        }
      } else {
        ushort_t* dst = (typ == 0) ? qr : kr;
        const float sgn = (l15 & 1) ? 1.f : -1.f;
#pragma unroll
        for (int m = 0; m < 4; ++m)
#pragma unroll
          for (int r = 0; r < 4; ++r) {
            const float val = acc[m][n][r];
            const float partner = __shfl_xor(val, 1);
            const int row = m0 + wr * 64 + m * 16 + l4 * 4 + r;
            const float2 cs = sctab[row * HD + d];
            dst[((size_t)h * N_TOK + row) * HD + d] = f2bf(val * cs.x + sgn * partner * cs.y);
          }
      }
    }
  }
}

// ---------------------------------------------------------------- GEMM2 body (shared), bf16 partial out
#define G2_BUF 32768

DEVFN int swz128(int p) { return p ^ (((p >> 7) & 7) << 4); }

DEVFN void g2_stage(const ushort_t* __restrict__ A, const ushort_t* __restrict__ BT,
                    int m0, int n0, int kt_el, char* buf, int tid) {
#pragma unroll
  for (int i = 0; i < 8; ++i) {
    const int p = i * 4096 + tid * 16;
    const bool isA = p < 16384;
    const int q = swz128(isA ? p : p - 16384);
    const int row = q >> 7, colel = (q & 127) >> 1;
    const ushort_t* src = (isA ? A + (size_t)(m0 + row) * ABCOLS
                               : BT + (size_t)(n0 + row) * ABCOLS) + kt_el + colel;
    gload(src, buf + i * 4096 + ((tid >> 6) << 10));
  }
}

DEVFN void g2_body(const ushort_t* __restrict__ A, const ushort_t* __restrict__ BT,
                   char* smem, int m0, int n0, int kt0, int NT,
                   ushort_t* __restrict__ outp, int tid) {
  const int l = tid & 63, l15 = l & 15, l4 = l >> 4;
  const int w = tid >> 6, wr = w >> 1, wc = w & 1;
  f32x4 acc[4][4] = {};

  g2_stage(A, BT, m0, n0, kt0, smem, tid);
  g2_stage(A, BT, m0, n0, kt0 + 64, smem + G2_BUF, tid);
  asm volatile("s_waitcnt vmcnt(8)" ::: "memory");
  __builtin_amdgcn_s_barrier();
  __builtin_amdgcn_sched_barrier(0);

  for (int t = 0; t < NT; ++t) {
    const char* bufA = smem + (t & 1) * G2_BUF;
    const char* bufB = bufA + 16384;
    bf16x8 af[4][2], bv[4][2];
#pragma unroll
    for (int kk = 0; kk < 2; ++kk) {
#pragma unroll
      for (int mi = 0; mi < 4; ++mi) {
        const int p = (wr * 64 + mi * 16 + l15) * 128 + kk * 64 + l4 * 16;
        af[mi][kk] = *(const bf16x8*)(bufA + swz128(p));
      }
#pragma unroll
      for (int ni = 0; ni < 4; ++ni) {
        const int p = (wc * 64 + ni * 16 + l15) * 128 + kk * 64 + l4 * 16;
        bv[ni][kk] = *(const bf16x8*)(bufB + swz128(p));
      }
    }
#pragma unroll
    for (int kk = 0; kk < 2; ++kk)
#pragma unroll
      for (int mi = 0; mi < 4; ++mi)
#pragma unroll
        for (int ni = 0; ni < 4; ++ni)
          acc[mi][ni] = __builtin_amdgcn_mfma_f32_16x16x32_bf16(af[mi][kk], bv[ni][kk], acc[mi][ni], 0, 0, 0);

    if (t == NT - 1) break;
    __builtin_amdgcn_sched_barrier(0);
    __builtin_amdgcn_s_barrier();
    if (t + 2 < NT) {
      g2_stage(A, BT, m0, n0, kt0 + (t + 2) * 64, smem + (t & 1) * G2_BUF, tid);
      asm volatile("s_waitcnt vmcnt(8)" ::: "memory");
    } else {
      asm volatile("s_waitcnt vmcnt(0)" ::: "memory");
    }
    __builtin_amdgcn_s_barrier();
    __builtin_amdgcn_sched_barrier(0);
  }

#pragma unroll
  for (int mi = 0; mi < 4; ++mi)
#pragma unroll
    for (int ni = 0; ni < 4; ++ni)
#pragma unroll
      for (int r = 0; r < 4; ++r) {
        const int row = m0 + wr * 64 + mi * 16 + l4 * 4 + r;
        const int col = n0 + wc * 64 + ni * 16 + l15;
        outp[(size_t)row * HDIM + col] = f2bf(acc[mi][ni][r]);
      }
}

// ---------------------------------------------------------------- attention one q-tile (wave-private)
DEVFN void attn_one(const ushort_t* __restrict__ qr, const ushort_t* __restrict__ kr,
                    const ushort_t* __restrict__ vT, ushort_t* __restrict__ ab,
                    int h, int seg, int qt, ushort_t* Pw, int l15, int l4) {
  const int qrow0 = seg * SEGLEN + qt * 16;
  bf16x8 aq[2];
#pragma unroll
  for (int kk = 0; kk < 2; ++kk)
    aq[kk] = *(const bf16x8*)(qr + ((size_t)h * N_TOK + qrow0 + l15) * HD + kk * 32 + l4 * 8);

  f32x4 o[4] = {};
  float m_run[4], l_run[4];
#pragma unroll
  for (int r = 0; r < 4; ++r) { m_run[r] = -1e30f; l_run[r] = 0.f; }

  const int kbmax = qt >> 2;
  for (int kb = 0; kb <= kbmax; ++kb) {
    bf16x8 bk[4][2];
#pragma unroll
    for (int ni = 0; ni < 4; ++ni)
#pragma unroll
      for (int kk = 0; kk < 2; ++kk)
        bk[ni][kk] = *(const bf16x8*)(kr + ((size_t)h * N_TOK + seg * SEGLEN + kb * 64 + ni * 16 + l15) * HD + kk * 32 + l4 * 8);
    f32x4 s[4] = {};
#pragma unroll
    for (int ni = 0; ni < 4; ++ni)
#pragma unroll
      for (int kk = 0; kk < 2; ++kk)
        s[ni] = __builtin_amdgcn_mfma_f32_16x16x32_bf16(aq[kk], bk[ni][kk], s[ni], 0, 0, 0);

    const bool diag = (kb == kbmax);
#pragma unroll
    for (int ni = 0; ni < 4; ++ni)
#pragma unroll
      for (int r = 0; r < 4; ++r) {
        float v = s[ni][r] * 0.125f;
        if (diag) {
          const int qrow = qt * 16 + l4 * 4 + r;
          const int jcol = kb * 64 + ni * 16 + l15;
          if (jcol > qrow) v = -1e30f;
        }
        s[ni][r] = v;
      }

    float sc_[4];
#pragma unroll
    for (int r = 0; r < 4; ++r) {
      float pm = fmaxf(fmaxf(s[0][r], s[1][r]), fmaxf(s[2][r], s[3][r]));
      pm = fmaxf(pm, __shfl_xor(pm, 1));
      pm = fmaxf(pm, __shfl_xor(pm, 2));
      pm = fmaxf(pm, __shfl_xor(pm, 4));
      pm = fmaxf(pm, __shfl_xor(pm, 8));
      const float mn = fmaxf(m_run[r], pm);
      sc_[r] = __expf(m_run[r] - mn);
      m_run[r] = mn;
    }
#pragma unroll
    for (int ni = 0; ni < 4; ++ni)
#pragma unroll
      for (int r = 0; r < 4; ++r)
        s[ni][r] = __expf(s[ni][r] - m_run[r]);
#pragma unroll
    for (int r = 0; r < 4; ++r) {
      float ls = s[0][r] + s[1][r] + s[2][r] + s[3][r];
      ls += __shfl_xor(ls, 1);
      ls += __shfl_xor(ls, 2);
      ls += __shfl_xor(ls, 4);
      ls += __shfl_xor(ls, 8);
      l_run[r] = l_run[r] * sc_[r] + ls;
    }
#pragma unroll
    for (int ni = 0; ni < 4; ++ni)
#pragma unroll
      for (int r = 0; r < 4; ++r)
        o[ni][r] *= sc_[r];

#pragma unroll
    for (int ni = 0; ni < 4; ++ni)
#pragma unroll
      for (int r = 0; r < 4; ++r)
        Pw[(l4 * 4 + r) * 64 + ni * 16 + l15] = f2bf(s[ni][r]);

    bf16x8 pa[2], bv[4][2];
#pragma unroll
    for (int k2 = 0; k2 < 2; ++k2)
      pa[k2] = *(const bf16x8*)(&Pw[l15 * 64 + k2 * 32 + l4 * 8]);
#pragma unroll
    for (int ni = 0; ni < 4; ++ni)
#pragma unroll
      for (int k2 = 0; k2 < 2; ++k2)
        bv[ni][k2] = *(const bf16x8*)(vT + ((size_t)h * HD + ni * 16 + l15) * N_TOK + seg * SEGLEN + kb * 64 + k2 * 32 + l4 * 8);
#pragma unroll
    for (int ni = 0; ni < 4; ++ni)
#pragma unroll
      for (int k2 = 0; k2 < 2; ++k2)
        o[ni] = __builtin_amdgcn_mfma_f32_16x16x32_bf16(pa[k2], bv[ni][k2], o[ni], 0, 0, 0);
  }

#pragma unroll
  for (int ni = 0; ni < 4; ++ni)
#pragma unroll
    for (int r = 0; r < 4; ++r) {
      const int row = qrow0 + l4 * 4 + r;
      const int col = h * HD + ni * 16 + l15;
      ab[(size_t)row * ABCOLS + col] = f2bf(o[ni][r] / l_run[r]);
    }
}

// ---------------------------------------------------------------- fused mid: attn (blocks 0..191) + gemm2 ff chunks (192..575)
__global__ __launch_bounds__(256) void fused_mid(
    const ushort_t* __restrict__ ab, const ushort_t* __restrict__ woutT,
    ushort_t* __restrict__ cpartb,
    const ushort_t* __restrict__ qr, const ushort_t* __restrict__ kr,
    const ushort_t* __restrict__ vT, ushort_t* __restrict__ ab_out) {
  __shared__ __align__(16) char smem[2 * G2_BUF];
  const int b = (int)blockIdx.x;
  const int tid = threadIdx.x;
  if (b < 192) {
    // attention: pair (z, 3-z) -> every wave exactly 5 kb-tiles
    const int h = b % NHEADS;
    const int r2 = b / NHEADS;            // 0..15
    const int seg = r2 & 7, p = r2 >> 3;  // p in {0,1}
    const int w = tid >> 6, l = tid & 63;
    const int l15 = l & 15, l4 = l >> 4;
    ushort_t* Pw = (ushort_t*)smem + w * (16 * 64);
    attn_one(qr, kr, vT, ab_out, h, seg, p * 4 + w, Pw, l15, l4);
    attn_one(qr, kr, vT, ab_out, h, seg, (3 - p) * 4 + w, Pw, l15, l4);
  } else {
    const int idx = b - 192;
    const int z = 1 + (idx / 96);         // ff chunks 1..4
    const int rem = idx % 96;
    const int n0 = (rem % 6) * 128, m0 = (rem / 6) * 128;
    g2_body(ab, woutT, smem, m0, n0, z * KCHUNK, 12,
            cpartb + (size_t)(z - 1) * N_TOK * HDIM, tid);
  }
}

// ---------------------------------------------------------------- gemm2 attn-column chunk (K 0..768, split in 2)
__global__ __launch_bounds__(256) void gemm2_z0(
    const ushort_t* __restrict__ ab, const ushort_t* __restrict__ woutT,
    ushort_t* __restrict__ cpartb) {
  __shared__ __align__(16) char smem[2 * G2_BUF];
  const int b = (int)blockIdx.x;
  const int half = b / 96, rem = b % 96;
  const int n0 = (rem % 6) * 128, m0 = (rem / 6) * 128;
  g2_body(ab, woutT, smem, m0, n0, half * 384, 6,
          cpartb + (size_t)(4 + half) * N_TOK * HDIM, threadIdx.x);
}

// ----------------------------------------------------------------
extern "C" void kernel_launch(void* const* d_in, const int* in_sizes, int n_in,
                              void* d_out, int out_size, void* d_ws, size_t ws_size,
                              hipStream_t stream) {
  const int*   tokens   = (const int*)d_in[0];
  const float* ages     = (const float*)d_in[1];
  const float* time_d   = (const float*)d_in[2];
  const float* embed    = (const float*)d_in[4];
  const float* in_nw    = (const float*)d_in[5];
  const float* out_nw   = (const float*)d_in[6];
  const float* layer_nw = (const float*)d_in[7];
  const float* Win      = (const float*)d_in[8];
  const float* Wout     = (const float*)d_in[9];
  float* out = (float*)d_out;

  char* ws = (char*)d_ws;
  float*    x      = (float*)   (ws + 0);            //  6,291,456
  ushort_t* hbuf   = (ushort_t*)(ws + 6291456);      //  3,145,728
  float2*   sctab  = (float2*)  (ws + 9437184);      //  1,048,576
  ushort_t* cpartb = (ushort_t*)(ws + 10485760);     // 18,874,368 (6 bf16 slices)
  ushort_t* ab     = (ushort_t*)(ws + 29360128);     // 15,728,640
  ushort_t* qrb    = (ushort_t*)(ws + 45088768);     //  3,145,728
  ushort_t* krb    = (ushort_t*)(ws + 48234496);     //  3,145,728
  ushort_t* vTb    = (ushort_t*)(ws + 51380224);     //  3,145,728
  ushort_t* winT   = (ushort_t*)(ws + 54525952);     // 25,952,256
  ushort_t* woutT  = (ushort_t*)(ws + 80478208);     // 11,796,480  (end 92,274,688)

  transpose_all<<<dim3(9216), dim3(32, 8), 0, stream>>>(Win, Wout, winT, woutT);
  rms_init<<<dim3(N_TOK), dim3(256), 0, stream>>>(embed, tokens, ages, in_nw, layer_nw,
                                                  time_d, x, hbuf, sctab);

  for (int lyr = 0; lyr < 2; ++lyr) {
    gemm1f<<<dim3(704), dim3(256), 0, stream>>>(hbuf, winT + (size_t)lyr * TCOLS * HDIM,
                                                sctab, ab, qrb, krb, vTb);
    fused_mid<<<dim3(576), dim3(256), 0, stream>>>(ab, woutT + (size_t)lyr * HDIM * ABCOLS,
                                                   cpartb, qrb, krb, vTb, ab);
    gemm2_z0<<<dim3(192), dim3(256), 0, stream>>>(ab, woutT + (size_t)lyr * HDIM * ABCOLS,
                                                  cpartb);
    if (lyr == 0)
      rms_fused<<<dim3(N_TOK), dim3(256), 0, stream>>>(cpartb, x, layer_nw + HDIM, time_d,
                                                       nullptr, hbuf, 1);
    else
      rms_fused<<<dim3(N_TOK), dim3(256), 0, stream>>>(cpartb, x, out_nw, nullptr,
                                                       out, nullptr, 2);
  }
}

// Round 8
// 184.114 us; speedup vs baseline: 1.2292x; 1.0131x over previous
//
#include <hip/hip_runtime.h>
#include <math.h>

typedef unsigned short ushort_t;
typedef float f32x4 __attribute__((ext_vector_type(4)));
typedef __bf16 bf16x8 __attribute__((ext_vector_type(8)));

#define DEVFN __device__ __forceinline__

DEVFN ushort_t f2bf(float f) {
  unsigned int u = __float_as_uint(f);
  u += 0x7FFFu + ((u >> 16) & 1u);   // round-to-nearest-even
  return (ushort_t)(u >> 16);
}
DEVFN float bf2f(ushort_t u) { return __uint_as_float((unsigned int)u << 16); }

DEVFN void gload(const ushort_t* src, char* dst) {
  __builtin_amdgcn_global_load_lds(
      (const __attribute__((address_space(1))) unsigned int*)src,
      (__attribute__((address_space(3))) unsigned int*)dst, 16, 0, 0);
}

#define N_TOK  2048
#define HDIM   768
#define TCOLS  8448     // 2*I + 3*H
#define FFI    3072
#define NHEADS 12
#define HD     64
#define NSEG   8
#define SEGLEN 256
#define ABCOLS 3840     // H + I
#define NPART  6        // 4 ff chunks (K=768) + 2 attn half-chunks (K=384)
#define KCHUNK 768

// ---------------------------------------------------------------- preamble: weight transpose+convert AND rms_init
// blocks [0,9216): transpose; [9216,11264): per-row rms_init
__global__ __launch_bounds__(256) void preamble(
    const float* __restrict__ Win, const float* __restrict__ Wout,
    ushort_t* __restrict__ winT, ushort_t* __restrict__ woutT,
    const float* __restrict__ embed, const int* __restrict__ tokens,
    const float* __restrict__ ages,
    const float* __restrict__ in_nw, const float* __restrict__ layer_nw,
    const float* __restrict__ time_data,
    float* __restrict__ x, ushort_t* __restrict__ hbuf, float2* __restrict__ sctab) {
  const int tid = threadIdx.x;
  if (blockIdx.x < 9216) {
    __shared__ ushort_t tile[32][66];
    int id = blockIdx.x;
    const float* in; ushort_t* out; int R, C, tr, tc;
    if (id < 6336) {                      // Win: 12 row-tiles x 264 col-tiles x 2
      const int z = id / 3168; id -= z * 3168;
      R = HDIM; C = TCOLS;
      tr = (id / 264) * 64; tc = (id % 264) * 32;
      in = Win + (size_t)z * R * C; out = winT + (size_t)z * R * C;
    } else {                              // Wout: 60 row-tiles x 24 col-tiles x 2
      id -= 6336;
      const int z = id / 1440; id -= z * 1440;
      R = ABCOLS; C = HDIM;
      tr = (id / 24) * 64; tc = (id % 24) * 32;
      in = Wout + (size_t)z * R * C; out = woutT + (size_t)z * R * C;
    }
    const int tx = tid & 31, ty = tid >> 5;   // 32 x 8
#pragma unroll
    for (int i = 0; i < 8; ++i) {
      const int r = ty + i * 8;
      tile[tx][r] = f2bf(in[(size_t)(tr + r) * C + tc + tx]);
    }
    __syncthreads();
#pragma unroll
    for (int i = 0; i < 4; ++i) {
      const int c = ty + i * 8;
      ushort2 pk; pk.x = tile[c][2 * tx]; pk.y = tile[c][2 * tx + 1];
      *(ushort2*)(out + (size_t)(tc + c) * R + tr + 2 * tx) = pk;
    }
    return;
  }
  // ---- rms_init (row per block)
  const int row = blockIdx.x - 9216;
  if (tid < 32) {                         // rope table for this row
    const int k = tid;
    const float e = (2.0f * (float)k) / 31.0f;
    const float t = ages[row] * expf(-e * logf(10000.0f));
    float2 cs; cs.x = cosf(t); cs.y = sinf(t);
    sctab[row * HD + 2 * k] = cs;
    sctab[row * HD + 2 * k + 1] = cs;
  }
  __shared__ float part[4];
  const float* src = embed + (size_t)tokens[row] * HDIM;
  float4 v = {0.f, 0.f, 0.f, 0.f};
  const int c0 = tid * 4;
  if (tid < 192) v = *(const float4*)(src + c0);
  float ss = v.x * v.x + v.y * v.y + v.z * v.z + v.w * v.w;
#pragma unroll
  for (int off = 1; off < 64; off <<= 1) ss += __shfl_xor(ss, off);
  if ((tid & 63) == 0) part[tid >> 6] = ss;
  __syncthreads();
  const float rs = rsqrtf((part[0] + part[1] + part[2] + part[3]) * (1.0f / HDIM) + 1e-6f);
  float4 y = {0.f, 0.f, 0.f, 0.f};
  if (tid < 192) {
    y.x = v.x * rs * in_nw[c0]; y.y = v.y * rs * in_nw[c0 + 1];
    y.z = v.z * rs * in_nw[c0 + 2]; y.w = v.w * rs * in_nw[c0 + 3];
    *(float4*)(x + (size_t)row * HDIM + c0) = y;
  }
  float ss2 = y.x * y.x + y.y * y.y + y.z * y.z + y.w * y.w;
#pragma unroll
  for (int off = 1; off < 64; off <<= 1) ss2 += __shfl_xor(ss2, off);
  __syncthreads();
  if ((tid & 63) == 0) part[tid >> 6] = ss2;
  __syncthreads();
  const float rs2 = rsqrtf((part[0] + part[1] + part[2] + part[3]) * (1.0f / HDIM) + 1e-6f);
  if (tid < 192) {
    float val[4];
#pragma unroll
    for (int j = 0; j < 4; ++j) {
      const int c = c0 + j;
      float vv = ((const float*)&y)[j] * rs2 * layer_nw[c];
      if (c >= HDIM - 4) {
        const float td = time_data[row * 2 + (c & 1)];
        vv = (c >= HDIM - 2) ? td * td : td;
      }
      val[j] = vv;
    }
    ushort4 pk;
    pk.x = f2bf(val[0]); pk.y = f2bf(val[1]); pk.z = f2bf(val[2]); pk.w = f2bf(val[3]);
    *(ushort4*)(hbuf + (size_t)row * HDIM + c0) = pk;
  }
}

// ---------------------------------------------------------------- fused reduce(6 bf16 partials) + residual + rms
__global__ __launch_bounds__(256) void rms_fused(
    const ushort_t* __restrict__ cpartb, float* __restrict__ x,
    const float* __restrict__ w, const float* __restrict__ time_data,
    float* __restrict__ out_f32, ushort_t* __restrict__ out_bf16, const int mode) {
  const int row = blockIdx.x;
  const size_t stride = (size_t)N_TOK * HDIM;
  const int tid = threadIdx.x;
  const int c0 = tid * 4;
  float4 s = {0.f, 0.f, 0.f, 0.f};
  if (tid < 192) {
    s = *(const float4*)(x + (size_t)row * HDIM + c0);
#pragma unroll
    for (int z = 0; z < NPART; ++z) {
      const ushort4 p = *(const ushort4*)(cpartb + z * stride + (size_t)row * HDIM + c0);
      s.x += bf2f(p.x); s.y += bf2f(p.y); s.z += bf2f(p.z); s.w += bf2f(p.w);
    }
    if (mode == 1) *(float4*)(x + (size_t)row * HDIM + c0) = s;
  }
  float ss = s.x * s.x + s.y * s.y + s.z * s.z + s.w * s.w;
#pragma unroll
  for (int off = 1; off < 64; off <<= 1) ss += __shfl_xor(ss, off);
  __shared__ float part[4];
  if ((tid & 63) == 0) part[tid >> 6] = ss;
  __syncthreads();
  const float rs = rsqrtf((part[0] + part[1] + part[2] + part[3]) * (1.0f / HDIM) + 1e-6f);
  if (tid < 192) {
    float val[4];
#pragma unroll
    for (int j = 0; j < 4; ++j) {
      const int c = c0 + j;
      float vv = ((const float*)&s)[j] * rs * w[c];
      if (mode == 1 && c >= HDIM - 4) {
        const float td = time_data[row * 2 + (c & 1)];
        vv = (c >= HDIM - 2) ? td * td : td;
      }
      val[j] = vv;
    }
    if (mode == 1) {
      ushort4 pk;
      pk.x = f2bf(val[0]); pk.y = f2bf(val[1]); pk.z = f2bf(val[2]); pk.w = f2bf(val[3]);
      *(ushort4*)(out_bf16 + (size_t)row * HDIM + c0) = pk;
    } else {
      float4 o; o.x = val[0]; o.y = val[1]; o.z = val[2]; o.w = val[3];
      *(float4*)(out_f32 + (size_t)row * HDIM + c0) = o;
    }
  }
}

// ---------------------------------------------------------------- GEMM1 fused (proven r6 structure)
#define G1_NT 24
#define G1_ABYT 8192
#define G1_BUF  20480

DEVFN int swz64(int p) {
  const int g = ((p >> 6) & 3) ^ ((p >> 8) & 3);
  return p ^ (g << 4);
}
DEVFN int ffmap(int vr) {
  return (vr < 2 * FFI) ? ((((vr >> 4) & 1) * FFI) + ((vr >> 5) << 4) + (vr & 15)) : vr;
}

DEVFN void g1f_stage(const ushort_t* __restrict__ A, const ushort_t* __restrict__ BT,
                     int m0, int n0, int kt_el, char* buf, int tid) {
#pragma unroll
  for (int i = 0; i < 2; ++i) {
    const int q = swz64(i * 4096 + tid * 16);
    gload(A + (size_t)(m0 + (q >> 6)) * HDIM + kt_el + ((q & 63) >> 1),
          buf + i * 4096 + ((tid >> 6) << 10));
  }
#pragma unroll
  for (int i = 0; i < 3; ++i) {
    const int q = swz64(i * 4096 + tid * 16);
    const int vr = n0 + (q >> 6);
    gload(BT + (size_t)ffmap(vr) * HDIM + kt_el + ((q & 63) >> 1),
          buf + G1_ABYT + i * 4096 + ((tid >> 6) << 10));
  }
}

__global__ __launch_bounds__(256, 3) void gemm1f(
    const ushort_t* __restrict__ A, const ushort_t* __restrict__ BT,
    const float2* __restrict__ sctab,
    ushort_t* __restrict__ ab, ushort_t* __restrict__ qr,
    ushort_t* __restrict__ kr, ushort_t* __restrict__ vT) {
  __shared__ __align__(16) char smem[2 * G1_BUF];
  const int tid = threadIdx.x;
  const int l = tid & 63, l15 = l & 15, l4 = l >> 4;
  const int wid = tid >> 6, wr = wid >> 1, wc = wid & 1;
  const int bid = (int)blockIdx.x;
  const int wg = (bid & 7) * 88 + (bid >> 3);
  const int nt = wg >> 4, mt = wg & 15;
  const int m0 = mt * 128, n0 = nt * 192;

  f32x4 acc[4][6] = {};

  g1f_stage(A, BT, m0, n0, 0,  smem, tid);
  g1f_stage(A, BT, m0, n0, 32, smem + G1_BUF, tid);
  asm volatile("s_waitcnt vmcnt(5)" ::: "memory");
  __builtin_amdgcn_s_barrier();
  __builtin_amdgcn_sched_barrier(0);

  for (int t = 0; t < G1_NT; ++t) {
    const char* bufA = smem + (t & 1) * G1_BUF;
    const char* bufB = bufA + G1_ABYT;
    bf16x8 a4[4], b6[6];
#pragma unroll
    for (int m = 0; m < 4; ++m) {
      const int p = (wr * 64 + m * 16 + l15) * 64 + l4 * 16;
      a4[m] = *(const bf16x8*)(bufA + swz64(p));
    }
#pragma unroll
    for (int n = 0; n < 6; ++n) {
      const int p = (wc * 96 + n * 16 + l15) * 64 + l4 * 16;
      b6[n] = *(const bf16x8*)(bufB + swz64(p));
    }
#pragma unroll
    for (int m = 0; m < 4; ++m)
#pragma unroll
      for (int n = 0; n < 6; ++n)
        acc[m][n] = __builtin_amdgcn_mfma_f32_16x16x32_bf16(a4[m], b6[n], acc[m][n], 0, 0, 0);

    if (t == G1_NT - 1) break;
    __builtin_amdgcn_sched_barrier(0);
    __builtin_amdgcn_s_barrier();
    if (t + 2 < G1_NT) {
      g1f_stage(A, BT, m0, n0, (t + 2) * 32, smem + (t & 1) * G1_BUF, tid);
      asm volatile("s_waitcnt vmcnt(5)" ::: "memory");
    } else {
      asm volatile("s_waitcnt vmcnt(0)" ::: "memory");
    }
    __builtin_amdgcn_s_barrier();
    __builtin_amdgcn_sched_barrier(0);
  }

  if (nt < 32) {
#pragma unroll
    for (int m = 0; m < 4; ++m)
#pragma unroll
      for (int np = 0; np < 3; ++np) {
        const int colj = (nt * 6 + wc * 3 + np) * 16 + l15;
#pragma unroll
        for (int r = 0; r < 4; ++r) {
          const float x1 = acc[m][2 * np][r], x2 = acc[m][2 * np + 1][r];
          const float sv = x1 / (1.f + __expf(-x1)) * x2;
          const int row = m0 + wr * 64 + m * 16 + l4 * 4 + r;
          ab[(size_t)row * ABCOLS + HDIM + colj] = f2bf(sv);
        }
      }
  } else {
#pragma unroll
    for (int n = 0; n < 6; ++n) {
      const int gcol = (nt - 32) * 192 + wc * 96 + n * 16;
      const int g = gcol >> 6;
      const int typ = g / NHEADS, h = g - typ * NHEADS;
      const int d = (gcol & 63) + l15;
      if (typ == 2) {
#pragma unroll
        for (int m = 0; m < 4; ++m) {
          ushort4 pk;
          pk.x = f2bf(acc[m][n][0]); pk.y = f2bf(acc[m][n][1]);
          pk.z = f2bf(acc[m][n][2]); pk.w = f2bf(acc[m][n][3]);
          const int row0 = m0 + wr * 64 + m * 16 + l4 * 4;
          *(ushort4*)(vT + ((size_t)h * HD + d) * N_TOK + row0) = pk;
        }
      } else {
        ushort_t* dst = (typ == 0) ? qr : kr;
        const float sgn = (l15 & 1) ? 1.f : -1.f;
#pragma unroll
        for (int m = 0; m < 4; ++m)
#pragma unroll
          for (int r = 0; r < 4; ++r) {
            const float val = acc[m][n][r];
            const float partner = __shfl_xor(val, 1);
            const int row = m0 + wr * 64 + m * 16 + l4 * 4 + r;
            const float2 cs = sctab[row * HD + d];
            dst[((size_t)h * N_TOK + row) * HD + d] = f2bf(val * cs.x + sgn * partner * cs.y);
          }
      }
    }
  }
}

// ---------------------------------------------------------------- GEMM2 body: 128x192 tile, BK=64, 2-deep
#define G2_BUF 40960          // A 16KB + B 24KB

DEVFN int swz128(int p) { return p ^ (((p >> 7) & 7) << 4); }

DEVFN void g2_stage(const ushort_t* __restrict__ A, const ushort_t* __restrict__ BT,
                    int m0, int n0, int kt_el, char* buf, int tid) {
#pragma unroll
  for (int i = 0; i < 10; ++i) {
    const int p = i * 4096 + tid * 16;
    const bool isA = p < 16384;
    const int q = swz128(isA ? p : p - 16384);
    const int row = q >> 7, colel = (q & 127) >> 1;
    const ushort_t* src = (isA ? A + (size_t)(m0 + row) * ABCOLS
                               : BT + (size_t)(n0 + row) * ABCOLS) + kt_el + colel;
    gload(src, buf + i * 4096 + ((tid >> 6) << 10));
  }
}

DEVFN void g2_body(const ushort_t* __restrict__ A, const ushort_t* __restrict__ BT,
                   char* smem, int m0, int n0, int kt0, int NT,
                   ushort_t* __restrict__ outp, int tid) {
  const int l = tid & 63, l15 = l & 15, l4 = l >> 4;
  const int w = tid >> 6, wr = w >> 1, wc = w & 1;
  f32x4 acc[4][6] = {};

  g2_stage(A, BT, m0, n0, kt0, smem, tid);
  g2_stage(A, BT, m0, n0, kt0 + 64, smem + G2_BUF, tid);
  asm volatile("s_waitcnt vmcnt(10)" ::: "memory");
  __builtin_amdgcn_s_barrier();
  __builtin_amdgcn_sched_barrier(0);

  for (int t = 0; t < NT; ++t) {
    const char* bufA = smem + (t & 1) * G2_BUF;
    const char* bufB = bufA + 16384;
#pragma unroll
    for (int kk = 0; kk < 2; ++kk) {
      bf16x8 af[4], bv[6];
#pragma unroll
      for (int mi = 0; mi < 4; ++mi) {
        const int p = (wr * 64 + mi * 16 + l15) * 128 + kk * 64 + l4 * 16;
        af[mi] = *(const bf16x8*)(bufA + swz128(p));
      }
#pragma unroll
      for (int ni = 0; ni < 6; ++ni) {
        const int p = (wc * 96 + ni * 16 + l15) * 128 + kk * 64 + l4 * 16;
        bv[ni] = *(const bf16x8*)(bufB + swz128(p));
      }
#pragma unroll
      for (int mi = 0; mi < 4; ++mi)
#pragma unroll
        for (int ni = 0; ni < 6; ++ni)
          acc[mi][ni] = __builtin_amdgcn_mfma_f32_16x16x32_bf16(af[mi], bv[ni], acc[mi][ni], 0, 0, 0);
    }

    if (t == NT - 1) break;
    __builtin_amdgcn_sched_barrier(0);
    __builtin_amdgcn_s_barrier();
    if (t + 2 < NT) {
      g2_stage(A, BT, m0, n0, kt0 + (t + 2) * 64, smem + (t & 1) * G2_BUF, tid);
      asm volatile("s_waitcnt vmcnt(10)" ::: "memory");
    } else {
      asm volatile("s_waitcnt vmcnt(0)" ::: "memory");
    }
    __builtin_amdgcn_s_barrier();
    __builtin_amdgcn_sched_barrier(0);
  }

#pragma unroll
  for (int mi = 0; mi < 4; ++mi)
#pragma unroll
    for (int ni = 0; ni < 6; ++ni)
#pragma unroll
      for (int r = 0; r < 4; ++r) {
        const int row = m0 + wr * 64 + mi * 16 + l4 * 4 + r;
        const int col = n0 + wc * 96 + ni * 16 + l15;
        outp[(size_t)row * HDIM + col] = f2bf(acc[mi][ni][r]);
      }
}

// ---------------------------------------------------------------- attention one q-tile (wave-private)
DEVFN void attn_one(const ushort_t* __restrict__ qr, const ushort_t* __restrict__ kr,
                    const ushort_t* __restrict__ vT, ushort_t* __restrict__ ab,
                    int h, int seg, int qt, ushort_t* Pw, int l15, int l4) {
  const int qrow0 = seg * SEGLEN + qt * 16;
  bf16x8 aq[2];
#pragma unroll
  for (int kk = 0; kk < 2; ++kk)
    aq[kk] = *(const bf16x8*)(qr + ((size_t)h * N_TOK + qrow0 + l15) * HD + kk * 32 + l4 * 8);

  f32x4 o[4] = {};
  float m_run[4], l_run[4];
#pragma unroll
  for (int r = 0; r < 4; ++r) { m_run[r] = -1e30f; l_run[r] = 0.f; }

  const int kbmax = qt >> 2;
  for (int kb = 0; kb <= kbmax; ++kb) {
    bf16x8 bk[4][2];
#pragma unroll
    for (int ni = 0; ni < 4; ++ni)
#pragma unroll
      for (int kk = 0; kk < 2; ++kk)
        bk[ni][kk] = *(const bf16x8*)(kr + ((size_t)h * N_TOK + seg * SEGLEN + kb * 64 + ni * 16 + l15) * HD + kk * 32 + l4 * 8);
    f32x4 s[4] = {};
#pragma unroll
    for (int ni = 0; ni < 4; ++ni)
#pragma unroll
      for (int kk = 0; kk < 2; ++kk)
        s[ni] = __builtin_amdgcn_mfma_f32_16x16x32_bf16(aq[kk], bk[ni][kk], s[ni], 0, 0, 0);

    const bool diag = (kb == kbmax);
#pragma unroll
    for (int ni = 0; ni < 4; ++ni)
#pragma unroll
      for (int r = 0; r < 4; ++r) {
        float v = s[ni][r] * 0.125f;
        if (diag) {
          const int qrow = qt * 16 + l4 * 4 + r;
          const int jcol = kb * 64 + ni * 16 + l15;
          if (jcol > qrow) v = -1e30f;
        }
        s[ni][r] = v;
      }

    float sc_[4];
#pragma unroll
    for (int r = 0; r < 4; ++r) {
      float pm = fmaxf(fmaxf(s[0][r], s[1][r]), fmaxf(s[2][r], s[3][r]));
      pm = fmaxf(pm, __shfl_xor(pm, 1));
      pm = fmaxf(pm, __shfl_xor(pm, 2));
      pm = fmaxf(pm, __shfl_xor(pm, 4));
      pm = fmaxf(pm, __shfl_xor(pm, 8));
      const float mn = fmaxf(m_run[r], pm);
      sc_[r] = __expf(m_run[r] - mn);
      m_run[r] = mn;
    }
#pragma unroll
    for (int ni = 0; ni < 4; ++ni)
#pragma unroll
      for (int r = 0; r < 4; ++r)
        s[ni][r] = __expf(s[ni][r] - m_run[r]);
#pragma unroll
    for (int r = 0; r < 4; ++r) {
      float ls = s[0][r] + s[1][r] + s[2][r] + s[3][r];
      ls += __shfl_xor(ls, 1);
      ls += __shfl_xor(ls, 2);
      ls += __shfl_xor(ls, 4);
      ls += __shfl_xor(ls, 8);
      l_run[r] = l_run[r] * sc_[r] + ls;
    }
#pragma unroll
    for (int ni = 0; ni < 4; ++ni)
#pragma unroll
      for (int r = 0; r < 4; ++r)
        o[ni][r] *= sc_[r];

#pragma unroll
    for (int ni = 0; ni < 4; ++ni)
#pragma unroll
      for (int r = 0; r < 4; ++r)
        Pw[(l4 * 4 + r) * 64 + ni * 16 + l15] = f2bf(s[ni][r]);

    bf16x8 pa[2], bv[4][2];
#pragma unroll
    for (int k2 = 0; k2 < 2; ++k2)
      pa[k2] = *(const bf16x8*)(&Pw[l15 * 64 + k2 * 32 + l4 * 8]);
#pragma unroll
    for (int ni = 0; ni < 4; ++ni)
#pragma unroll
      for (int k2 = 0; k2 < 2; ++k2)
        bv[ni][k2] = *(const bf16x8*)(vT + ((size_t)h * HD + ni * 16 + l15) * N_TOK + seg * SEGLEN + kb * 64 + k2 * 32 + l4 * 8);
#pragma unroll
    for (int ni = 0; ni < 4; ++ni)
#pragma unroll
      for (int k2 = 0; k2 < 2; ++k2)
        o[ni] = __builtin_amdgcn_mfma_f32_16x16x32_bf16(pa[k2], bv[ni][k2], o[ni], 0, 0, 0);
  }

#pragma unroll
  for (int ni = 0; ni < 4; ++ni)
#pragma unroll
    for (int r = 0; r < 4; ++r) {
      const int row = qrow0 + l4 * 4 + r;
      const int col = h * HD + ni * 16 + l15;
      ab[(size_t)row * ABCOLS + col] = f2bf(o[ni][r] / l_run[r]);
    }
}

// ---------------------------------------------------------------- fused mid: 448 blocks; b%7<3 -> attn, else gemm2 ff
__global__ __launch_bounds__(256, 2) void fused_mid(
    const ushort_t* __restrict__ ab, const ushort_t* __restrict__ woutT,
    ushort_t* __restrict__ cpartb,
    const ushort_t* __restrict__ qr, const ushort_t* __restrict__ kr,
    const ushort_t* __restrict__ vT, ushort_t* __restrict__ ab_out) {
  __shared__ __align__(16) char smem[2 * G2_BUF];     // 80 KiB
  const int b = (int)blockIdx.x;
  const int tid = threadIdx.x;
  const int sel = b % 7;
  if (sel < 3) {
    const int a = (b / 7) * 3 + sel;      // 0..191
    const int h = a % NHEADS;
    const int r2 = a / NHEADS;            // 0..15
    const int seg = r2 & 7, p = r2 >> 3;  // p in {0,1}
    const int w = tid >> 6, l = tid & 63;
    const int l15 = l & 15, l4 = l >> 4;
    ushort_t* Pw = (ushort_t*)smem + w * (16 * 64);
    attn_one(qr, kr, vT, ab_out, h, seg, p * 4 + w, Pw, l15, l4);
    attn_one(qr, kr, vT, ab_out, h, seg, (3 - p) * 4 + w, Pw, l15, l4);
  } else {
    const int f = (b / 7) * 4 + (sel - 3);   // 0..255
    const int z = 1 + (f >> 6);              // ff chunks 1..4
    const int rem = f & 63;
    const int n0 = (rem & 3) * 192, m0 = (rem >> 2) * 128;
    g2_body(ab, woutT, smem, m0, n0, z * KCHUNK, 12,
            cpartb + (size_t)(z - 1) * N_TOK * HDIM, tid);
  }
}

// ---------------------------------------------------------------- gemm2 attn-column chunk (K 0..768, split in 2)
__global__ __launch_bounds__(256, 2) void gemm2_z0(
    const ushort_t* __restrict__ ab, const ushort_t* __restrict__ woutT,
    ushort_t* __restrict__ cpartb) {
  __shared__ __align__(16) char smem[2 * G2_BUF];
  const int b = (int)blockIdx.x;
  const int half = b >> 6, rem = b & 63;
  const int n0 = (rem & 3) * 192, m0 = (rem >> 2) * 128;
  g2_body(ab, woutT, smem, m0, n0, half * 384, 6,
          cpartb + (size_t)(4 + half) * N_TOK * HDIM, threadIdx.x);
}

// ----------------------------------------------------------------
extern "C" void kernel_launch(void* const* d_in, const int* in_sizes, int n_in,
                              void* d_out, int out_size, void* d_ws, size_t ws_size,
                              hipStream_t stream) {
  const int*   tokens   = (const int*)d_in[0];
  const float* ages     = (const float*)d_in[1];
  const float* time_d   = (const float*)d_in[2];
  const float* embed    = (const float*)d_in[4];
  const float* in_nw    = (const float*)d_in[5];
  const float* out_nw   = (const float*)d_in[6];
  const float* layer_nw = (const float*)d_in[7];
  const float* Win      = (const float*)d_in[8];
  const float* Wout     = (const float*)d_in[9];
  float* out = (float*)d_out;

  char* ws = (char*)d_ws;
  float*    x      = (float*)   (ws + 0);            //  6,291,456
  ushort_t* hbuf   = (ushort_t*)(ws + 6291456);      //  3,145,728
  float2*   sctab  = (float2*)  (ws + 9437184);      //  1,048,576
  ushort_t* cpartb = (ushort_t*)(ws + 10485760);     // 18,874,368 (6 bf16 slices)
  ushort_t* ab     = (ushort_t*)(ws + 29360128);     // 15,728,640
  ushort_t* qrb    = (ushort_t*)(ws + 45088768);     //  3,145,728
  ushort_t* krb    = (ushort_t*)(ws + 48234496);     //  3,145,728
  ushort_t* vTb    = (ushort_t*)(ws + 51380224);     //  3,145,728
  ushort_t* winT   = (ushort_t*)(ws + 54525952);     // 25,952,256
  ushort_t* woutT  = (ushort_t*)(ws + 80478208);     // 11,796,480  (end 92,274,688)

  preamble<<<dim3(11264), dim3(256), 0, stream>>>(Win, Wout, winT, woutT,
                                                  embed, tokens, ages, in_nw, layer_nw,
                                                  time_d, x, hbuf, sctab);

  for (int lyr = 0; lyr < 2; ++lyr) {
    gemm1f<<<dim3(704), dim3(256), 0, stream>>>(hbuf, winT + (size_t)lyr * TCOLS * HDIM,
                                                sctab, ab, qrb, krb, vTb);
    fused_mid<<<dim3(448), dim3(256), 0, stream>>>(ab, woutT + (size_t)lyr * HDIM * ABCOLS,
                                                   cpartb, qrb, krb, vTb, ab);
    gemm2_z0<<<dim3(128), dim3(256), 0, stream>>>(ab, woutT + (size_t)lyr * HDIM * ABCOLS,
                                                  cpartb);
    if (lyr == 0)
      rms_fused<<<dim3(N_TOK), dim3(256), 0, stream>>>(cpartb, x, layer_nw + HDIM, time_d,
                                                       nullptr, hbuf, 1);
    else
      rms_fused<<<dim3(N_TOK), dim3(256), 0, stream>>>(cpartb, x, out_nw, nullptr,
                                                       out, nullptr, 2);
  }
}

// Round 9
// 179.438 us; speedup vs baseline: 1.2612x; 1.0261x over previous
//
#include <hip/hip_runtime.h>
#include <math.h>

typedef unsigned short ushort_t;
typedef float f32x4 __attribute__((ext_vector_type(4)));
typedef __bf16 bf16x8 __attribute__((ext_vector_type(8)));

#define DEVFN __device__ __forceinline__

DEVFN ushort_t f2bf(float f) {
  unsigned int u = __float_as_uint(f);
  u += 0x7FFFu + ((u >> 16) & 1u);   // round-to-nearest-even
  return (ushort_t)(u >> 16);
}
DEVFN float bf2f(ushort_t u) { return __uint_as_float((unsigned int)u << 16); }

DEVFN void gload(const ushort_t* src, char* dst) {
  __builtin_amdgcn_global_load_lds(
      (const __attribute__((address_space(1))) unsigned int*)src,
      (__attribute__((address_space(3))) unsigned int*)dst, 16, 0, 0);
}

#define N_TOK  2048
#define HDIM   768
#define TCOLS  8448     // 2*I + 3*H
#define FFI    3072
#define NHEADS 12
#define HD     64
#define NSEG   8
#define SEGLEN 256
#define ABCOLS 3840     // H + I
#define NPART  6        // 4 ff chunks (K=768) + 2 attn half-chunks (K=384)
#define KCHUNK 768

// ---------------------------------------------------------------- 64x32 transpose tile (shared helper)
// in: f32 [R x C] row-major; out: bf16 [C x R]; one 64(row) x 32(col) tile.
DEVFN void transpose_tile(const float* __restrict__ in, ushort_t* __restrict__ out,
                          int R, int C, int tr, int tc, int tid, char* smem) {
  ushort_t (*tile)[66] = (ushort_t(*)[66])smem;
  const int tx = tid & 31, ty = tid >> 5;   // 32 x 8
#pragma unroll
  for (int i = 0; i < 8; ++i) {
    const int r = ty + i * 8;
    tile[tx][r] = f2bf(in[(size_t)(tr + r) * C + tc + tx]);
  }
  __syncthreads();
#pragma unroll
  for (int i = 0; i < 4; ++i) {
    const int c = ty + i * 8;
    ushort2 pk; pk.x = tile[c][2 * tx]; pk.y = tile[c][2 * tx + 1];
    *(ushort2*)(out + (size_t)(tc + c) * R + tr + 2 * tx) = pk;
  }
}

// ---------------------------------------------------------------- preamble: winT-0 transpose + rms_init
// blocks [0,3168): winT layer-0 transpose; [3168,5216): per-row rms_init
__global__ __launch_bounds__(256) void preamble(
    const float* __restrict__ Win, ushort_t* __restrict__ winT,
    const float* __restrict__ embed, const int* __restrict__ tokens,
    const float* __restrict__ ages,
    const float* __restrict__ in_nw, const float* __restrict__ layer_nw,
    const float* __restrict__ time_data,
    float* __restrict__ x, ushort_t* __restrict__ hbuf, float2* __restrict__ sctab) {
  const int tid = threadIdx.x;
  if (blockIdx.x < 3168) {
    __shared__ char tsmem[32 * 66 * 2];
    const int id = blockIdx.x;
    transpose_tile(Win, winT, HDIM, TCOLS, (id / 264) * 64, (id % 264) * 32, tid, tsmem);
    return;
  }
  // ---- rms_init (row per block)
  const int row = blockIdx.x - 3168;
  if (tid < 32) {                         // rope table for this row
    const int k = tid;
    const float e = (2.0f * (float)k) / 31.0f;
    const float t = ages[row] * expf(-e * logf(10000.0f));
    float2 cs; cs.x = cosf(t); cs.y = sinf(t);
    sctab[row * HD + 2 * k] = cs;
    sctab[row * HD + 2 * k + 1] = cs;
  }
  __shared__ float part[4];
  const float* src = embed + (size_t)tokens[row] * HDIM;
  float4 v = {0.f, 0.f, 0.f, 0.f};
  const int c0 = tid * 4;
  if (tid < 192) v = *(const float4*)(src + c0);
  float ss = v.x * v.x + v.y * v.y + v.z * v.z + v.w * v.w;
#pragma unroll
  for (int off = 1; off < 64; off <<= 1) ss += __shfl_xor(ss, off);
  if ((tid & 63) == 0) part[tid >> 6] = ss;
  __syncthreads();
  const float rs = rsqrtf((part[0] + part[1] + part[2] + part[3]) * (1.0f / HDIM) + 1e-6f);
  float4 y = {0.f, 0.f, 0.f, 0.f};
  if (tid < 192) {
    y.x = v.x * rs * in_nw[c0]; y.y = v.y * rs * in_nw[c0 + 1];
    y.z = v.z * rs * in_nw[c0 + 2]; y.w = v.w * rs * in_nw[c0 + 3];
    *(float4*)(x + (size_t)row * HDIM + c0) = y;
  }
  float ss2 = y.x * y.x + y.y * y.y + y.z * y.z + y.w * y.w;
#pragma unroll
  for (int off = 1; off < 64; off <<= 1) ss2 += __shfl_xor(ss2, off);
  __syncthreads();
  if ((tid & 63) == 0) part[tid >> 6] = ss2;
  __syncthreads();
  const float rs2 = rsqrtf((part[0] + part[1] + part[2] + part[3]) * (1.0f / HDIM) + 1e-6f);
  if (tid < 192) {
    float val[4];
#pragma unroll
    for (int j = 0; j < 4; ++j) {
      const int c = c0 + j;
      float vv = ((const float*)&y)[j] * rs2 * layer_nw[c];
      if (c >= HDIM - 4) {
        const float td = time_data[row * 2 + (c & 1)];
        vv = (c >= HDIM - 2) ? td * td : td;
      }
      val[j] = vv;
    }
    ushort4 pk;
    pk.x = f2bf(val[0]); pk.y = f2bf(val[1]); pk.z = f2bf(val[2]); pk.w = f2bf(val[3]);
    *(ushort4*)(hbuf + (size_t)row * HDIM + c0) = pk;
  }
}

// ---------------------------------------------------------------- fused reduce(6 bf16 partials) + residual + rms
__global__ __launch_bounds__(256) void rms_fused(
    const ushort_t* __restrict__ cpartb, float* __restrict__ x,
    const float* __restrict__ w, const float* __restrict__ time_data,
    float* __restrict__ out_f32, ushort_t* __restrict__ out_bf16, const int mode) {
  const int row = blockIdx.x;
  const size_t stride = (size_t)N_TOK * HDIM;
  const int tid = threadIdx.x;
  const int c0 = tid * 4;
  float4 s = {0.f, 0.f, 0.f, 0.f};
  if (tid < 192) {
    s = *(const float4*)(x + (size_t)row * HDIM + c0);
#pragma unroll
    for (int z = 0; z < NPART; ++z) {
      const ushort4 p = *(const ushort4*)(cpartb + z * stride + (size_t)row * HDIM + c0);
      s.x += bf2f(p.x); s.y += bf2f(p.y); s.z += bf2f(p.z); s.w += bf2f(p.w);
    }
    if (mode == 1) *(float4*)(x + (size_t)row * HDIM + c0) = s;
  }
  float ss = s.x * s.x + s.y * s.y + s.z * s.z + s.w * s.w;
#pragma unroll
  for (int off = 1; off < 64; off <<= 1) ss += __shfl_xor(ss, off);
  __shared__ float part[4];
  if ((tid & 63) == 0) part[tid >> 6] = ss;
  __syncthreads();
  const float rs = rsqrtf((part[0] + part[1] + part[2] + part[3]) * (1.0f / HDIM) + 1e-6f);
  if (tid < 192) {
    float val[4];
#pragma unroll
    for (int j = 0; j < 4; ++j) {
      const int c = c0 + j;
      float vv = ((const float*)&s)[j] * rs * w[c];
      if (mode == 1 && c >= HDIM - 4) {
        const float td = time_data[row * 2 + (c & 1)];
        vv = (c >= HDIM - 2) ? td * td : td;
      }
      val[j] = vv;
    }
    if (mode == 1) {
      ushort4 pk;
      pk.x = f2bf(val[0]); pk.y = f2bf(val[1]); pk.z = f2bf(val[2]); pk.w = f2bf(val[3]);
      *(ushort4*)(out_bf16 + (size_t)row * HDIM + c0) = pk;
    } else {
      float4 o; o.x = val[0]; o.y = val[1]; o.z = val[2]; o.w = val[3];
      *(float4*)(out_f32 + (size_t)row * HDIM + c0) = o;
    }
  }
}

// ---------------------------------------------------------------- GEMM1 fused + piggyback transposes
#define G1_NT 24
#define G1_ABYT 8192
#define G1_BUF  20480

DEVFN int swz64(int p) {
  const int g = ((p >> 6) & 3) ^ ((p >> 8) & 3);
  return p ^ (g << 4);
}
DEVFN int ffmap(int vr) {
  return (vr < 2 * FFI) ? ((((vr >> 4) & 1) * FFI) + ((vr >> 5) << 4) + (vr & 15)) : vr;
}

DEVFN void g1f_stage(const ushort_t* __restrict__ A, const ushort_t* __restrict__ BT,
                     int m0, int n0, int kt_el, char* buf, int tid) {
#pragma unroll
  for (int i = 0; i < 2; ++i) {
    const int q = swz64(i * 4096 + tid * 16);
    gload(A + (size_t)(m0 + (q >> 6)) * HDIM + kt_el + ((q & 63) >> 1),
          buf + i * 4096 + ((tid >> 6) << 10));
  }
#pragma unroll
  for (int i = 0; i < 3; ++i) {
    const int q = swz64(i * 4096 + tid * 16);
    const int vr = n0 + (q >> 6);
    gload(BT + (size_t)ffmap(vr) * HDIM + kt_el + ((q & 63) >> 1),
          buf + G1_ABYT + i * 4096 + ((tid >> 6) << 10));
  }
}

// extra blocks (bid>=704): e<1440 -> transpose job1 (Wout->woutT, 60x24 tiles);
// else -> job2 (Win lyr1 -> winT lyr1, 12x264 tiles)
__global__ __launch_bounds__(256, 3) void gemm1f(
    const ushort_t* __restrict__ A, const ushort_t* __restrict__ BT,
    const float2* __restrict__ sctab,
    ushort_t* __restrict__ ab, ushort_t* __restrict__ qr,
    ushort_t* __restrict__ kr, ushort_t* __restrict__ vT,
    const float* __restrict__ tj1_src, ushort_t* __restrict__ tj1_dst,
    const float* __restrict__ tj2_src, ushort_t* __restrict__ tj2_dst) {
  __shared__ __align__(16) char smem[2 * G1_BUF];
  const int tid = threadIdx.x;
  const int bid = (int)blockIdx.x;
  if (bid >= 704) {
    int e = bid - 704;
    if (e < 1440)
      transpose_tile(tj1_src, tj1_dst, ABCOLS, HDIM, (e / 24) * 64, (e % 24) * 32, tid, smem);
    else {
      e -= 1440;
      transpose_tile(tj2_src, tj2_dst, HDIM, TCOLS, (e / 264) * 64, (e % 264) * 32, tid, smem);
    }
    return;
  }
  const int l = tid & 63, l15 = l & 15, l4 = l >> 4;
  const int wid = tid >> 6, wr = wid >> 1, wc = wid & 1;
  const int wg = (bid & 7) * 88 + (bid >> 3);
  const int nt = wg >> 4, mt = wg & 15;
  const int m0 = mt * 128, n0 = nt * 192;

  f32x4 acc[4][6] = {};

  g1f_stage(A, BT, m0, n0, 0,  smem, tid);
  g1f_stage(A, BT, m0, n0, 32, smem + G1_BUF, tid);
  asm volatile("s_waitcnt vmcnt(5)" ::: "memory");
  __builtin_amdgcn_s_barrier();
  __builtin_amdgcn_sched_barrier(0);

  for (int t = 0; t < G1_NT; ++t) {
    const char* bufA = smem + (t & 1) * G1_BUF;
    const char* bufB = bufA + G1_ABYT;
    bf16x8 a4[4], b6[6];
#pragma unroll
    for (int m = 0; m < 4; ++m) {
      const int p = (wr * 64 + m * 16 + l15) * 64 + l4 * 16;
      a4[m] = *(const bf16x8*)(bufA + swz64(p));
    }
#pragma unroll
    for (int n = 0; n < 6; ++n) {
      const int p = (wc * 96 + n * 16 + l15) * 64 + l4 * 16;
      b6[n] = *(const bf16x8*)(bufB + swz64(p));
    }
#pragma unroll
    for (int m = 0; m < 4; ++m)
#pragma unroll
      for (int n = 0; n < 6; ++n)
        acc[m][n] = __builtin_amdgcn_mfma_f32_16x16x32_bf16(a4[m], b6[n], acc[m][n], 0, 0, 0);

    if (t == G1_NT - 1) break;
    __builtin_amdgcn_sched_barrier(0);
    __builtin_amdgcn_s_barrier();
    if (t + 2 < G1_NT) {
      g1f_stage(A, BT, m0, n0, (t + 2) * 32, smem + (t & 1) * G1_BUF, tid);
      asm volatile("s_waitcnt vmcnt(5)" ::: "memory");
    } else {
      asm volatile("s_waitcnt vmcnt(0)" ::: "memory");
    }
    __builtin_amdgcn_s_barrier();
    __builtin_amdgcn_sched_barrier(0);
  }

  if (nt < 32) {
#pragma unroll
    for (int m = 0; m < 4; ++m)
#pragma unroll
      for (int np = 0; np < 3; ++np) {
        const int colj = (nt * 6 + wc * 3 + np) * 16 + l15;
#pragma unroll
        for (int r = 0; r < 4; ++r) {
          const float x1 = acc[m][2 * np][r], x2 = acc[m][2 * np + 1][r];
          const float sv = x1 / (1.f + __expf(-x1)) * x2;
          const int row = m0 + wr * 64 + m * 16 + l4 * 4 + r;
          ab[(size_t)row * ABCOLS + HDIM + colj] = f2bf(sv);
        }
      }
  } else {
#pragma unroll
    for (int n = 0; n < 6; ++n) {
      const int gcol = (nt - 32) * 192 + wc * 96 + n * 16;
      const int g = gcol >> 6;
      const int typ = g / NHEADS, h = g - typ * NHEADS;
      const int d = (gcol & 63) + l15;
      if (typ == 2) {
#pragma unroll
        for (int m = 0; m < 4; ++m) {
          ushort4 pk;
          pk.x = f2bf(acc[m][n][0]); pk.y = f2bf(acc[m][n][1]);
          pk.z = f2bf(acc[m][n][2]); pk.w = f2bf(acc[m][n][3]);
          const int row0 = m0 + wr * 64 + m * 16 + l4 * 4;
          *(ushort4*)(vT + ((size_t)h * HD + d) * N_TOK + row0) = pk;
        }
      } else {
        ushort_t* dst = (typ == 0) ? qr : kr;
        const float sgn = (l15 & 1) ? 1.f : -1.f;
#pragma unroll
        for (int m = 0; m < 4; ++m)
#pragma unroll
          for (int r = 0; r < 4; ++r) {
            const float val = acc[m][n][r];
            const float partner = __shfl_xor(val, 1);
            const int row = m0 + wr * 64 + m * 16 + l4 * 4 + r;
            const float2 cs = sctab[row * HD + d];
            dst[((size_t)h * N_TOK + row) * HD + d] = f2bf(val * cs.x + sgn * partner * cs.y);
          }
      }
    }
  }
}

// ---------------------------------------------------------------- GEMM2 body: 128x192 tile, BK=64, 2-deep
#define G2_BUF 40960          // A 16KB + B 24KB

DEVFN int swz128(int p) { return p ^ (((p >> 7) & 7) << 4); }

DEVFN void g2_stage(const ushort_t* __restrict__ A, const ushort_t* __restrict__ BT,
                    int m0, int n0, int kt_el, char* buf, int tid) {
#pragma unroll
  for (int i = 0; i < 10; ++i) {
    const int p = i * 4096 + tid * 16;
    const bool isA = p < 16384;
    const int q = swz128(isA ? p : p - 16384);
    const int row = q >> 7, colel = (q & 127) >> 1;
    const ushort_t* src = (isA ? A + (size_t)(m0 + row) * ABCOLS
                               : BT + (size_t)(n0 + row) * ABCOLS) + kt_el + colel;
    gload(src, buf + i * 4096 + ((tid >> 6) << 10));
  }
}

DEVFN void g2_body(const ushort_t* __restrict__ A, const ushort_t* __restrict__ BT,
                   char* smem, int m0, int n0, int kt0, int NT,
                   ushort_t* __restrict__ outp, int tid) {
  const int l = tid & 63, l15 = l & 15, l4 = l >> 4;
  const int w = tid >> 6, wr = w >> 1, wc = w & 1;
  f32x4 acc[4][6] = {};

  g2_stage(A, BT, m0, n0, kt0, smem, tid);
  g2_stage(A, BT, m0, n0, kt0 + 64, smem + G2_BUF, tid);
  asm volatile("s_waitcnt vmcnt(10)" ::: "memory");
  __builtin_amdgcn_s_barrier();
  __builtin_amdgcn_sched_barrier(0);

  for (int t = 0; t < NT; ++t) {
    const char* bufA = smem + (t & 1) * G2_BUF;
    const char* bufB = bufA + 16384;
#pragma unroll
    for (int kk = 0; kk < 2; ++kk) {
      bf16x8 af[4], bv[6];
#pragma unroll
      for (int mi = 0; mi < 4; ++mi) {
        const int p = (wr * 64 + mi * 16 + l15) * 128 + kk * 64 + l4 * 16;
        af[mi] = *(const bf16x8*)(bufA + swz128(p));
      }
#pragma unroll
      for (int ni = 0; ni < 6; ++ni) {
        const int p = (wc * 96 + ni * 16 + l15) * 128 + kk * 64 + l4 * 16;
        bv[ni] = *(const bf16x8*)(bufB + swz128(p));
      }
#pragma unroll
      for (int mi = 0; mi < 4; ++mi)
#pragma unroll
        for (int ni = 0; ni < 6; ++ni)
          acc[mi][ni] = __builtin_amdgcn_mfma_f32_16x16x32_bf16(af[mi], bv[ni], acc[mi][ni], 0, 0, 0);
    }

    if (t == NT - 1) break;
    __builtin_amdgcn_sched_barrier(0);
    __builtin_amdgcn_s_barrier();
    if (t + 2 < NT) {
      g2_stage(A, BT, m0, n0, kt0 + (t + 2) * 64, smem + (t & 1) * G2_BUF, tid);
      asm volatile("s_waitcnt vmcnt(10)" ::: "memory");
    } else {
      asm volatile("s_waitcnt vmcnt(0)" ::: "memory");
    }
    __builtin_amdgcn_s_barrier();
    __builtin_amdgcn_sched_barrier(0);
  }

#pragma unroll
  for (int mi = 0; mi < 4; ++mi)
#pragma unroll
    for (int ni = 0; ni < 6; ++ni)
#pragma unroll
      for (int r = 0; r < 4; ++r) {
        const int row = m0 + wr * 64 + mi * 16 + l4 * 4 + r;
        const int col = n0 + wc * 96 + ni * 16 + l15;
        outp[(size_t)row * HDIM + col] = f2bf(acc[mi][ni][r]);
      }
}

// ---------------------------------------------------------------- attention one q-tile (wave-private)
DEVFN void attn_one(const ushort_t* __restrict__ qr, const ushort_t* __restrict__ kr,
                    const ushort_t* __restrict__ vT, ushort_t* __restrict__ ab,
                    int h, int seg, int qt, ushort_t* Pw, int l15, int l4) {
  const int qrow0 = seg * SEGLEN + qt * 16;
  bf16x8 aq[2];
#pragma unroll
  for (int kk = 0; kk < 2; ++kk)
    aq[kk] = *(const bf16x8*)(qr + ((size_t)h * N_TOK + qrow0 + l15) * HD + kk * 32 + l4 * 8);

  f32x4 o[4] = {};
  float m_run[4], l_run[4];
#pragma unroll
  for (int r = 0; r < 4; ++r) { m_run[r] = -1e30f; l_run[r] = 0.f; }

  const int kbmax = qt >> 2;
  for (int kb = 0; kb <= kbmax; ++kb) {
    bf16x8 bk[4][2];
#pragma unroll
    for (int ni = 0; ni < 4; ++ni)
#pragma unroll
      for (int kk = 0; kk < 2; ++kk)
        bk[ni][kk] = *(const bf16x8*)(kr + ((size_t)h * N_TOK + seg * SEGLEN + kb * 64 + ni * 16 + l15) * HD + kk * 32 + l4 * 8);
    f32x4 s[4] = {};
#pragma unroll
    for (int ni = 0; ni < 4; ++ni)
#pragma unroll
      for (int kk = 0; kk < 2; ++kk)
        s[ni] = __builtin_amdgcn_mfma_f32_16x16x32_bf16(aq[kk], bk[ni][kk], s[ni], 0, 0, 0);

    const bool diag = (kb == kbmax);
#pragma unroll
    for (int ni = 0; ni < 4; ++ni)
#pragma unroll
      for (int r = 0; r < 4; ++r) {
        float v = s[ni][r] * 0.125f;
        if (diag) {
          const int qrow = qt * 16 + l4 * 4 + r;
          const int jcol = kb * 64 + ni * 16 + l15;
          if (jcol > qrow) v = -1e30f;
        }
        s[ni][r] = v;
      }

    float sc_[4];
#pragma unroll
    for (int r = 0; r < 4; ++r) {
      float pm = fmaxf(fmaxf(s[0][r], s[1][r]), fmaxf(s[2][r], s[3][r]));
      pm = fmaxf(pm, __shfl_xor(pm, 1));
      pm = fmaxf(pm, __shfl_xor(pm, 2));
      pm = fmaxf(pm, __shfl_xor(pm, 4));
      pm = fmaxf(pm, __shfl_xor(pm, 8));
      const float mn = fmaxf(m_run[r], pm);
      sc_[r] = __expf(m_run[r] - mn);
      m_run[r] = mn;
    }
#pragma unroll
    for (int ni = 0; ni < 4; ++ni)
#pragma unroll
      for (int r = 0; r < 4; ++r)
        s[ni][r] = __expf(s[ni][r] - m_run[r]);
#pragma unroll
    for (int r = 0; r < 4; ++r) {
      float ls = s[0][r] + s[1][r] + s[2][r] + s[3][r];
      ls += __shfl_xor(ls, 1);
      ls += __shfl_xor(ls, 2);
      ls += __shfl_xor(ls, 4);
      ls += __shfl_xor(ls, 8);
      l_run[r] = l_run[r] * sc_[r] + ls;
    }
#pragma unroll
    for (int ni = 0; ni < 4; ++ni)
#pragma unroll
      for (int r = 0; r < 4; ++r)
        o[ni][r] *= sc_[r];

#pragma unroll
    for (int ni = 0; ni < 4; ++ni)
#pragma unroll
      for (int r = 0; r < 4; ++r)
        Pw[(l4 * 4 + r) * 64 + ni * 16 + l15] = f2bf(s[ni][r]);

    bf16x8 pa[2], bv[4][2];
#pragma unroll
    for (int k2 = 0; k2 < 2; ++k2)
      pa[k2] = *(const bf16x8*)(&Pw[l15 * 64 + k2 * 32 + l4 * 8]);
#pragma unroll
    for (int ni = 0; ni < 4; ++ni)
#pragma unroll
      for (int k2 = 0; k2 < 2; ++k2)
        bv[ni][k2] = *(const bf16x8*)(vT + ((size_t)h * HD + ni * 16 + l15) * N_TOK + seg * SEGLEN + kb * 64 + k2 * 32 + l4 * 8);
#pragma unroll
    for (int ni = 0; ni < 4; ++ni)
#pragma unroll
      for (int k2 = 0; k2 < 2; ++k2)
        o[ni] = __builtin_amdgcn_mfma_f32_16x16x32_bf16(pa[k2], bv[ni][k2], o[ni], 0, 0, 0);
  }

#pragma unroll
  for (int ni = 0; ni < 4; ++ni)
#pragma unroll
    for (int r = 0; r < 4; ++r) {
      const int row = qrow0 + l4 * 4 + r;
      const int col = h * HD + ni * 16 + l15;
      ab[(size_t)row * ABCOLS + col] = f2bf(o[ni][r] / l_run[r]);
    }
}

// ---------------------------------------------------------------- fused mid: 448 blocks (b%7<3 attn, else gemm2) + extra transposes
__global__ __launch_bounds__(256, 2) void fused_mid(
    const ushort_t* __restrict__ ab, const ushort_t* __restrict__ woutT,
    ushort_t* __restrict__ cpartb,
    const ushort_t* __restrict__ qr, const ushort_t* __restrict__ kr,
    const ushort_t* __restrict__ vT, ushort_t* __restrict__ ab_out,
    const float* __restrict__ tj_src, ushort_t* __restrict__ tj_dst) {
  __shared__ __align__(16) char smem[2 * G2_BUF];     // 80 KiB
  const int b = (int)blockIdx.x;
  const int tid = threadIdx.x;
  if (b >= 448) {
    const int e = b - 448;
    transpose_tile(tj_src, tj_dst, ABCOLS, HDIM, (e / 24) * 64, (e % 24) * 32, tid, smem);
    return;
  }
  const int sel = b % 7;
  if (sel < 3) {
    const int a = (b / 7) * 3 + sel;      // 0..191
    const int h = a % NHEADS;
    const int r2 = a / NHEADS;            // 0..15
    const int seg = r2 & 7, p = r2 >> 3;  // p in {0,1}
    const int w = tid >> 6, l = tid & 63;
    const int l15 = l & 15, l4 = l >> 4;
    ushort_t* Pw = (ushort_t*)smem + w * (16 * 64);
    attn_one(qr, kr, vT, ab_out, h, seg, p * 4 + w, Pw, l15, l4);
    attn_one(qr, kr, vT, ab_out, h, seg, (3 - p) * 4 + w, Pw, l15, l4);
  } else {
    const int f = (b / 7) * 4 + (sel - 3);   // 0..255
    const int z = 1 + (f >> 6);              // ff chunks 1..4
    const int rem = f & 63;
    const int n0 = (rem & 3) * 192, m0 = (rem >> 2) * 128;
    g2_body(ab, woutT, smem, m0, n0, z * KCHUNK, 12,
            cpartb + (size_t)(z - 1) * N_TOK * HDIM, tid);
  }
}

// ---------------------------------------------------------------- gemm2 attn-column chunk (K 0..768, split in 2)
__global__ __launch_bounds__(256, 2) void gemm2_z0(
    const ushort_t* __restrict__ ab, const ushort_t* __restrict__ woutT,
    ushort_t* __restrict__ cpartb) {
  __shared__ __align__(16) char smem[2 * G2_BUF];
  const int b = (int)blockIdx.x;
  const int half = b >> 6, rem = b & 63;
  const int n0 = (rem & 3) * 192, m0 = (rem >> 2) * 128;
  g2_body(ab, woutT, smem, m0, n0, half * 384, 6,
          cpartb + (size_t)(4 + half) * N_TOK * HDIM, threadIdx.x);
}

// ----------------------------------------------------------------
extern "C" void kernel_launch(void* const* d_in, const int* in_sizes, int n_in,
                              void* d_out, int out_size, void* d_ws, size_t ws_size,
                              hipStream_t stream) {
  const int*   tokens   = (const int*)d_in[0];
  const float* ages     = (const float*)d_in[1];
  const float* time_d   = (const float*)d_in[2];
  const float* embed    = (const float*)d_in[4];
  const float* in_nw    = (const float*)d_in[5];
  const float* out_nw   = (const float*)d_in[6];
  const float* layer_nw = (const float*)d_in[7];
  const float* Win      = (const float*)d_in[8];
  const float* Wout     = (const float*)d_in[9];
  float* out = (float*)d_out;

  char* ws = (char*)d_ws;
  float*    x      = (float*)   (ws + 0);            //  6,291,456
  ushort_t* hbuf   = (ushort_t*)(ws + 6291456);      //  3,145,728
  float2*   sctab  = (float2*)  (ws + 9437184);      //  1,048,576
  ushort_t* cpartb = (ushort_t*)(ws + 10485760);     // 18,874,368 (6 bf16 slices)
  ushort_t* ab     = (ushort_t*)(ws + 29360128);     // 15,728,640
  ushort_t* qrb    = (ushort_t*)(ws + 45088768);     //  3,145,728
  ushort_t* krb    = (ushort_t*)(ws + 48234496);     //  3,145,728
  ushort_t* vTb    = (ushort_t*)(ws + 51380224);     //  3,145,728
  ushort_t* winT   = (ushort_t*)(ws + 54525952);     // 25,952,256
  ushort_t* woutT  = (ushort_t*)(ws + 80478208);     // 11,796,480  (end 92,274,688)

  const size_t winStride  = (size_t)TCOLS * HDIM;
  const size_t woutStride = (size_t)HDIM * ABCOLS;

  preamble<<<dim3(5216), dim3(256), 0, stream>>>(Win, winT, embed, tokens, ages,
                                                 in_nw, layer_nw, time_d, x, hbuf, sctab);

  for (int lyr = 0; lyr < 2; ++lyr) {
    if (lyr == 0) {
      // piggyback: woutT-0 (1440) + winT-1 (3168) transposes
      gemm1f<<<dim3(704 + 4608), dim3(256), 0, stream>>>(
          hbuf, winT, sctab, ab, qrb, krb, vTb,
          Wout, woutT, Win + winStride, winT + winStride);
      // piggyback: woutT-1 (1440)
      fused_mid<<<dim3(448 + 1440), dim3(256), 0, stream>>>(
          ab, woutT, cpartb, qrb, krb, vTb, ab,
          Wout + woutStride, woutT + woutStride);
    } else {
      gemm1f<<<dim3(704), dim3(256), 0, stream>>>(
          hbuf, winT + winStride, sctab, ab, qrb, krb, vTb,
          nullptr, nullptr, nullptr, nullptr);
      fused_mid<<<dim3(448), dim3(256), 0, stream>>>(
          ab, woutT + woutStride, cpartb, qrb, krb, vTb, ab,
          nullptr, nullptr);
    }
    gemm2_z0<<<dim3(128), dim3(256), 0, stream>>>(ab, woutT + lyr * woutStride, cpartb);
    if (lyr == 0)
      rms_fused<<<dim3(N_TOK), dim3(256), 0, stream>>>(cpartb, x, layer_nw + HDIM, time_d,
                                                       nullptr, hbuf, 1);
    else
      rms_fused<<<dim3(N_TOK), dim3(256), 0, stream>>>(cpartb, x, out_nw, nullptr,
                                                       out, nullptr, 2);
  }
}